// Round 4
// baseline (1311.856 us; speedup 1.0000x reference)
//
#include <hip/hip_runtime.h>
#include <hip/hip_bf16.h>
#include <math.h>

#define N_NODES 50000
#define N_EDGES 800000
#define TOT_EDGES (N_EDGES + N_NODES)
#define NEG_SLOPE 0.2f
#define M_PAD 50048
#define N_CHUNKS ((N_NODES + 1023) / 1024)

typedef __attribute__((ext_vector_type(8))) short bf16x8;
typedef __attribute__((ext_vector_type(4))) float f32x4;

__device__ __forceinline__ unsigned short f2bf(float f){
  union { float f; unsigned u; } x; x.f = f;
  unsigned r = x.u + 0x7FFF + ((x.u >> 16) & 1);
  return (unsigned short)(r >> 16);
}
__device__ __forceinline__ float bf2f(unsigned short h){
  union { unsigned u; float f; } x; x.u = ((unsigned)h) << 16;
  return x.f;
}
__device__ __forceinline__ void gl_lds16(const void* g, void* l){
  __builtin_amdgcn_global_load_lds(
    (const __attribute__((address_space(1))) unsigned int*)g,
    (__attribute__((address_space(3))) unsigned int*)l, 16, 0, 0);
}

// ---------------- CSR build ----------------

__global__ void hist_kernel(const int* __restrict__ ei, int* __restrict__ counts){
  int e = blockIdx.x*256 + threadIdx.x;
  if (e >= TOT_EDGES) return;
  int d = (e < N_EDGES) ? ei[N_EDGES + e] : (e - N_EDGES);
  atomicAdd(&counts[d], 1);
}

__global__ void scan1_kernel(const int* __restrict__ counts, int* __restrict__ partial,
                             int* __restrict__ chunksum){
  __shared__ int sm[1024];
  int t = threadIdx.x;
  int idx = blockIdx.x*1024 + t;
  int v = (idx < N_NODES) ? counts[idx] : 0;
  sm[t] = v;
  __syncthreads();
  for (int off = 1; off < 1024; off <<= 1){
    int u = (t >= off) ? sm[t-off] : 0;
    __syncthreads();
    sm[t] += u;
    __syncthreads();
  }
  if (idx < N_NODES) partial[idx] = sm[t];
  if (t == 1023) chunksum[blockIdx.x] = sm[1023];
}

__global__ void scan2_kernel(const int* __restrict__ chunksum, int* __restrict__ carry){
  if (threadIdx.x == 0){
    int c = 0;
    for (int i = 0; i < N_CHUNKS; ++i){ carry[i] = c; c += chunksum[i]; }
  }
}

__global__ void scan3_kernel(const int* __restrict__ partial, const int* __restrict__ counts,
                             const int* __restrict__ carry, int* __restrict__ offsets,
                             int* __restrict__ cursor){
  int idx = blockIdx.x*256 + threadIdx.x;
  if (idx >= N_NODES) return;
  int inc = partial[idx] + carry[idx >> 10];
  offsets[idx+1] = inc;
  cursor[idx] = inc - counts[idx];
  if (idx == 0) offsets[0] = 0;
}

__global__ void scatter_kernel(const int* __restrict__ ei, int* __restrict__ cursor,
                               int* __restrict__ ssrc){
  int e = blockIdx.x*256 + threadIdx.x;
  if (e >= TOT_EDGES) return;
  int s, d;
  if (e < N_EDGES){ s = ei[e]; d = ei[N_EDGES+e]; } else { s = e - N_EDGES; d = s; }
  int pos = atomicAdd(&cursor[d], 1);
  ssrc[pos] = s;
}

// ---------------- weight split+transpose: BT[n][k] = B[k][n] as bf16 hi/lo ----------------

__global__ void convert_BT(const float* __restrict__ B, unsigned short* __restrict__ BTh,
                           unsigned short* __restrict__ BTl, int K, int N){
  int id = blockIdx.x*256 + threadIdx.x;
  if (id >= K*N) return;
  int n = id / K, k = id - n*K;
  float v = B[(size_t)k*N + n];
  unsigned short h = f2bf(v);
  unsigned short l = f2bf(v - bf2f(h));
  BTh[id] = h; BTl[id] = l;
}

// layer-2 weights [512,40] -> padded BT2 [128][512]
__global__ void convert_BT2(const float* __restrict__ B, unsigned short* __restrict__ BTh,
                            unsigned short* __restrict__ BTl){
  int id = blockIdx.x*256 + threadIdx.x;
  if (id >= 128*512) return;
  int n = id >> 9, k = id & 511;
  float v = (n < 40) ? B[(size_t)k*40 + n] : 0.f;
  unsigned short h = f2bf(v);
  unsigned short l = f2bf(v - bf2f(h));
  BTh[id] = h; BTl[id] = l;
}

// ---------------- split-bf16 MFMA GEMM + fused attn-coef + bf16 output ----------------
// 128x128 tile, BK=32, 4 waves, 3-term split (Ah*Bh + Al*Bh + Ah*Bl)

__global__ __launch_bounds__(256, 2) void mfma_gemm(
    const float* __restrict__ A, const unsigned short* __restrict__ BTh,
    const unsigned short* __restrict__ BTl, float* __restrict__ C,
    unsigned short* __restrict__ Fb,
    const float* __restrict__ att_s, const float* __restrict__ att_d,
    float* __restrict__ asrc, float* __restrict__ adst,
    int M, int K, int Nc)
{
  __shared__ unsigned short sAh[128*32];
  __shared__ unsigned short sAl[128*32];
  __shared__ unsigned short sBh[128*32];
  __shared__ unsigned short sBl[128*32];

  const int tid = threadIdx.x;
  const int lane = tid & 63;
  const int wid = tid >> 6;
  const int wr = wid >> 1, wc = wid & 1;
  const int bm = blockIdx.y * 128, bn = blockIdx.x * 128;
  const int lr = lane & 15, kg = lane >> 4;

  const float* aread[4];
  int awoff[4];
  #pragma unroll
  for (int i = 0; i < 4; ++i){
    int o = tid + i*256;
    int row = o >> 3, ch = o & 7;
    int gr = bm + row; if (gr > M-1) gr = M-1;
    aread[i] = A + (size_t)gr*K + ch*4;
    int sc = (ch >> 1) ^ ((row >> 1) & 3);
    awoff[i] = row*32 + sc*8 + (ch & 1)*4;
  }
  size_t bgoff[2];
  #pragma unroll
  for (int i = 0; i < 2; ++i){
    int o = tid + i*256;
    int row = o >> 2, ch = o & 3;
    int sc = ch ^ ((row >> 1) & 3);
    bgoff[i] = (size_t)(bn + row)*K + sc*8;
  }
  int aoff[4], boff[4];
  #pragma unroll
  for (int i = 0; i < 4; ++i){
    int row = wr*64 + i*16 + lr;
    aoff[i] = row*32 + (kg ^ ((row >> 1) & 3))*8;
    int col = wc*64 + i*16 + lr;
    boff[i] = col*32 + (kg ^ ((col >> 1) & 3))*8;
  }

  float4 areg[4];
  auto loadA = [&](int k0){
    #pragma unroll
    for (int i = 0; i < 4; ++i)
      areg[i] = *(const float4*)(aread[i] + k0);
  };
  auto writeA = [&](){
    #pragma unroll
    for (int i = 0; i < 4; ++i){
      float4 v = areg[i];
      ushort4 h, l;
      h.x = f2bf(v.x); l.x = f2bf(v.x - bf2f(h.x));
      h.y = f2bf(v.y); l.y = f2bf(v.y - bf2f(h.y));
      h.z = f2bf(v.z); l.z = f2bf(v.z - bf2f(h.z));
      h.w = f2bf(v.w); l.w = f2bf(v.w - bf2f(h.w));
      *(ushort4*)&sAh[awoff[i]] = h;
      *(ushort4*)&sAl[awoff[i]] = l;
    }
  };
  auto stageB = [&](int k0){
    #pragma unroll
    for (int i = 0; i < 2; ++i){
      gl_lds16(BTh + bgoff[i] + k0, &sBh[(tid + i*256)*8]);
      gl_lds16(BTl + bgoff[i] + k0, &sBl[(tid + i*256)*8]);
    }
  };

  f32x4 acc[4][4];
  #pragma unroll
  for (int i = 0; i < 4; ++i)
    #pragma unroll
    for (int j = 0; j < 4; ++j)
      acc[i][j] = (f32x4){0.f, 0.f, 0.f, 0.f};

  loadA(0); writeA(); stageB(0);
  __syncthreads();
  int k0 = 0;
  while (true){
    int kn = k0 + 32;
    if (kn < K) loadA(kn);
    bf16x8 ah[4], al[4], bh[4], bl[4];
    #pragma unroll
    for (int i = 0; i < 4; ++i){
      ah[i] = *(const bf16x8*)&sAh[aoff[i]];
      al[i] = *(const bf16x8*)&sAl[aoff[i]];
      bh[i] = *(const bf16x8*)&sBh[boff[i]];
      bl[i] = *(const bf16x8*)&sBl[boff[i]];
    }
    #pragma unroll
    for (int i = 0; i < 4; ++i)
      #pragma unroll
      for (int j = 0; j < 4; ++j){
        acc[i][j] = __builtin_amdgcn_mfma_f32_16x16x32_bf16(ah[i], bh[j], acc[i][j], 0, 0, 0);
        acc[i][j] = __builtin_amdgcn_mfma_f32_16x16x32_bf16(al[i], bh[j], acc[i][j], 0, 0, 0);
        acc[i][j] = __builtin_amdgcn_mfma_f32_16x16x32_bf16(ah[i], bl[j], acc[i][j], 0, 0, 0);
      }
    if (kn >= K) break;
    __syncthreads();
    writeA();
    stageB(kn);
    __syncthreads();
    k0 = kn;
  }

  // fused attention coefficients: each wave owns exactly one head's 64 cols
  if (att_s){
    int head = (bn >> 6) + wc;
    float ws_[4], wd_[4];
    #pragma unroll
    for (int j = 0; j < 4; ++j){
      ws_[j] = att_s[head*64 + j*16 + lr];
      wd_[j] = att_d[head*64 + j*16 + lr];
    }
    #pragma unroll
    for (int i = 0; i < 4; ++i){
      #pragma unroll
      for (int r = 0; r < 4; ++r){
        float vs = 0.f, vd = 0.f;
        #pragma unroll
        for (int j = 0; j < 4; ++j){
          vs += acc[i][j][r] * ws_[j];
          vd += acc[i][j][r] * wd_[j];
        }
        #pragma unroll
        for (int m = 1; m < 16; m <<= 1){
          vs += __shfl_xor(vs, m);
          vd += __shfl_xor(vd, m);
        }
        int gm = bm + wr*64 + i*16 + kg*4 + r;
        if ((lane & 15) == 0 && gm < M){
          asrc[gm*8 + head] = vs;
          adst[gm*8 + head] = vd;
        }
      }
    }
  }

  // epilogue: C/D layout col=lane&15, row=(lane>>4)*4+reg  [m89]
  #pragma unroll
  for (int i = 0; i < 4; ++i){
    int gm0 = bm + wr*64 + i*16 + kg*4;
    #pragma unroll
    for (int j = 0; j < 4; ++j){
      int gn = bn + wc*64 + j*16 + lr;
      #pragma unroll
      for (int r = 0; r < 4; ++r){
        int gm = gm0 + r;
        if (gm < M){
          if (C && gn < Nc) C[(size_t)gm*Nc + gn] = acc[i][j][r];
          if (Fb) Fb[(size_t)gm*512 + gn] = f2bf(acc[i][j][r]);
        }
      }
    }
  }
}

// ---------------- softmax stats: one wave per dst; 8 edge-groups x 8 heads ----------------

__global__ __launch_bounds__(256) void softmax_stats(const int* __restrict__ offsets,
    const int* __restrict__ ssrc, const float* __restrict__ asrc,
    const float* __restrict__ adst, float* __restrict__ mx, float* __restrict__ inv){
  int w = threadIdx.x >> 6;
  int lane = threadIdx.x & 63;
  int d = blockIdx.x*4 + w;
  if (d >= N_NODES) return;
  int h = lane & 7, grp = lane >> 3;
  int beg = offsets[d], end = offsets[d+1];
  float ad = adst[d*8+h];
  float pm = -1e30f;
  for (int i = beg+grp; i < end; i += 8){
    int s = ssrc[i];
    float e = asrc[s*8+h] + ad;
    e = (e > 0.f) ? e : NEG_SLOPE*e;
    pm = fmaxf(pm, e);
  }
  pm = fmaxf(pm, __shfl_xor(pm, 8));
  pm = fmaxf(pm, __shfl_xor(pm, 16));
  pm = fmaxf(pm, __shfl_xor(pm, 32));
  float ps = 0.f;
  for (int i = beg+grp; i < end; i += 8){
    int s = ssrc[i];
    float e = asrc[s*8+h] + ad;
    e = (e > 0.f) ? e : NEG_SLOPE*e;
    ps += __expf(e - pm);
  }
  ps += __shfl_xor(ps, 8);
  ps += __shfl_xor(ps, 16);
  ps += __shfl_xor(ps, 32);
  if (grp == 0){ mx[d*8+h] = pm; inv[d*8+h] = 1.f/ps; }
}

// ---------------- channel-sliced SpMM: grid(dst_chunks, 16 slices of 32ch) ----------------
// slice-major dispatch => active gather footprint 50048 rows x 64B = 3.2MB < 4MB L2/XCD

__global__ __launch_bounds__(256) void spmm_kernel(const unsigned short* __restrict__ Fb,
    const int* __restrict__ offsets, const int* __restrict__ ssrc,
    const float* __restrict__ asrc, const float* __restrict__ adst,
    const float* __restrict__ mx, const float* __restrict__ inv,
    const float* __restrict__ bias, float* __restrict__ OUT, int do_relu){
  int slice = blockIdx.y;
  int h = slice >> 1;
  int c = slice*32 + (threadIdx.x & 31);
  int g = threadIdx.x >> 5;
  int d = blockIdx.x*8 + g;
  if (d >= N_NODES) return;
  int beg = offsets[d], end = offsets[d+1];
  float ad = adst[d*8+h];
  float m  = mx[d*8+h];
  float iv = inv[d*8+h];
  float acc = 0.f;
  int i = beg;
  for (; i+2 <= end; i += 2){
    int s0 = ssrc[i], s1 = ssrc[i+1];
    float f0 = bf2f(Fb[(size_t)s0*512 + c]);
    float f1 = bf2f(Fb[(size_t)s1*512 + c]);
    float e0 = asrc[s0*8+h] + ad; e0 = (e0>0.f)?e0:NEG_SLOPE*e0;
    float e1 = asrc[s1*8+h] + ad; e1 = (e1>0.f)?e1:NEG_SLOPE*e1;
    acc += __expf(e0-m)*iv * f0;
    acc += __expf(e1-m)*iv * f1;
  }
  for (; i < end; ++i){
    int s = ssrc[i];
    float e = asrc[s*8+h] + ad; e = (e>0.f)?e:NEG_SLOPE*e;
    acc += __expf(e-m)*iv * bf2f(Fb[(size_t)s*512 + c]);
  }
  float o = acc + bias[c];
  if (do_relu) o = fmaxf(o, 0.f);
  OUT[(size_t)d*512 + c] = o;
}

// ---------------- layer 2: H=1 C=40 ----------------

__global__ void attn_coef2_kernel(const float* __restrict__ H2v, const float* __restrict__ as2,
                                  const float* __restrict__ ad2,
                                  float* __restrict__ asrc, float* __restrict__ adst){
  int gid = blockIdx.x*256 + threadIdx.x;
  int node = gid >> 6;
  int lane = threadIdx.x & 63;
  if (node >= N_NODES) return;
  float v = 0.f, ws = 0.f, wd = 0.f;
  if (lane < 40){ v = H2v[(size_t)node*40 + lane]; ws = as2[lane]; wd = ad2[lane]; }
  float vs = v*ws, vd = v*wd;
  #pragma unroll
  for (int off = 32; off > 0; off >>= 1){
    vs += __shfl_down(vs, off);
    vd += __shfl_down(vd, off);
  }
  if (lane == 0){ asrc[node] = vs; adst[node] = vd; }
}

__global__ __launch_bounds__(64) void aggregate2_kernel(const float* __restrict__ H2v,
    const int* __restrict__ offsets, const int* __restrict__ ssrc,
    const float* __restrict__ asrc, const float* __restrict__ adst,
    const float* __restrict__ bias, float* __restrict__ OUT){
  int d = blockIdx.x;
  int lane = threadIdx.x;
  int beg = offsets[d], end = offsets[d+1];
  int deg = end - beg;
  float ad = adst[d];
  float pm = -1e30f;
  for (int i = lane; i < deg; i += 64){
    int s = ssrc[beg+i];
    float e = asrc[s] + ad; e = (e>0.f)?e:NEG_SLOPE*e;
    pm = fmaxf(pm, e);
  }
  #pragma unroll
  for (int off = 32; off > 0; off >>= 1) pm = fmaxf(pm, __shfl_xor(pm, off));
  float ps = 0.f;
  for (int i = lane; i < deg; i += 64){
    int s = ssrc[beg+i];
    float e = asrc[s] + ad; e=(e>0.f)?e:NEG_SLOPE*e;
    ps += __expf(e - pm);
  }
  #pragma unroll
  for (int off = 32; off > 0; off >>= 1) ps += __shfl_xor(ps, off);
  float inv = 1.f/ps;
  __shared__ float alS[64];
  __shared__ int sS[64];
  float acc = 0.f;
  for (int i0 = 0; i0 < deg; i0 += 64){
    int nch = min(64, deg - i0);
    if (lane < nch){
      int s = ssrc[beg+i0+lane];
      float e = asrc[s]+ad; e=(e>0.f)?e:NEG_SLOPE*e;
      alS[lane] = __expf(e-pm)*inv;
      sS[lane] = s;
    }
    __syncthreads();
    for (int i = 0; i < nch; ++i){
      if (lane < 40) acc += alS[i] * H2v[(size_t)sS[i]*40 + lane];
    }
    __syncthreads();
  }
  float logit = (lane<40) ? (acc + bias[lane]) : -1e30f;
  float mm = logit;
  #pragma unroll
  for (int off = 32; off > 0; off >>= 1) mm = fmaxf(mm, __shfl_xor(mm, off));
  float ex = (lane<40) ? __expf(logit-mm) : 0.f;
  float ss = ex;
  #pragma unroll
  for (int off = 32; off > 0; off >>= 1) ss += __shfl_xor(ss, off);
  if (lane < 40) OUT[(size_t)d*40 + lane] = logit - mm - logf(ss);
}

// ---------------- launch ----------------

extern "C" void kernel_launch(void* const* d_in, const int* in_sizes, int n_in,
                              void* d_out, int out_size, void* d_ws, size_t ws_size,
                              hipStream_t stream){
  const float* x   = (const float*)d_in[0];
  const int*   ei  = (const int*)d_in[1];
  const float* W0  = (const float*)d_in[2];
  const float* as0 = (const float*)d_in[3];
  const float* ad0 = (const float*)d_in[4];
  const float* b0  = (const float*)d_in[5];
  const float* W1  = (const float*)d_in[6];
  const float* as1 = (const float*)d_in[7];
  const float* ad1 = (const float*)d_in[8];
  const float* b1  = (const float*)d_in[9];
  const float* W2  = (const float*)d_in[10];
  const float* as2 = (const float*)d_in[11];
  const float* ad2 = (const float*)d_in[12];
  const float* b2  = (const float*)d_in[13];
  float* out = (float*)d_out;

  char* p = (char*)d_ws;
  auto alloc = [&](size_t bytes)->void*{
    void* r = (void*)p; p += (bytes + 255) & ~(size_t)255; return r;
  };
  float* F1    = (float*)alloc((size_t)M_PAD*512*4);
  unsigned short* Fb = (unsigned short*)alloc((size_t)M_PAD*512*2);
  float* ASRC  = (float*)alloc((size_t)N_NODES*8*4);
  float* ADST  = (float*)alloc((size_t)N_NODES*8*4);
  float* MX    = (float*)alloc((size_t)N_NODES*8*4);
  float* INV   = (float*)alloc((size_t)N_NODES*8*4);
  float* H2v   = (float*)alloc((size_t)N_NODES*40*4);
  float* ASRC2 = (float*)alloc((size_t)N_NODES*4);
  float* ADST2 = (float*)alloc((size_t)N_NODES*4);
  int* counts  = (int*)alloc((size_t)N_NODES*4);
  int* offsets = (int*)alloc((size_t)(N_NODES+1)*4);
  int* cursor  = (int*)alloc((size_t)N_NODES*4);
  int* ssrc    = (int*)alloc((size_t)TOT_EDGES*4);
  int* partial = (int*)alloc((size_t)N_NODES*4);
  int* chunksum= (int*)alloc(64*4);
  int* carry   = (int*)alloc(64*4);
  unsigned short* BTh  = (unsigned short*)alloc((size_t)512*512*2);
  unsigned short* BTl  = (unsigned short*)alloc((size_t)512*512*2);
  unsigned short* BT2h = (unsigned short*)alloc((size_t)128*512*2);
  unsigned short* BT2l = (unsigned short*)alloc((size_t)128*512*2);

  // CSR build (same graph for all 3 layers)
  hipMemsetAsync(counts, 0, (size_t)N_NODES*4, stream);
  hist_kernel<<<(TOT_EDGES+255)/256, 256, 0, stream>>>(ei, counts);
  scan1_kernel<<<N_CHUNKS, 1024, 0, stream>>>(counts, partial, chunksum);
  scan2_kernel<<<1, 64, 0, stream>>>(chunksum, carry);
  scan3_kernel<<<(N_NODES+255)/256, 256, 0, stream>>>(partial, counts, carry, offsets, cursor);
  scatter_kernel<<<(TOT_EDGES+255)/256, 256, 0, stream>>>(ei, cursor, ssrc);

  int mt = M_PAD / 128;   // 391
  dim3 spmm_grid((N_NODES + 7) / 8, 16);

  // layer 0: x[50000,128] @ W0[128,512]
  convert_BT<<<(128*512+255)/256, 256, 0, stream>>>(W0, BTh, BTl, 128, 512);
  mfma_gemm<<<dim3(4, mt), 256, 0, stream>>>(x, BTh, BTl, nullptr, Fb,
                                             as0, ad0, ASRC, ADST, N_NODES, 128, 512);
  softmax_stats<<<(N_NODES+3)/4, 256, 0, stream>>>(offsets, ssrc, ASRC, ADST, MX, INV);
  spmm_kernel<<<spmm_grid, 256, 0, stream>>>(Fb, offsets, ssrc, ASRC, ADST, MX, INV, b0, F1, 1);

  // layer 1: F1[50000,512] @ W1[512,512]
  convert_BT<<<(512*512+255)/256, 256, 0, stream>>>(W1, BTh, BTl, 512, 512);
  mfma_gemm<<<dim3(4, mt), 256, 0, stream>>>(F1, BTh, BTl, nullptr, Fb,
                                             as1, ad1, ASRC, ADST, N_NODES, 512, 512);
  softmax_stats<<<(N_NODES+3)/4, 256, 0, stream>>>(offsets, ssrc, ASRC, ADST, MX, INV);
  spmm_kernel<<<spmm_grid, 256, 0, stream>>>(Fb, offsets, ssrc, ASRC, ADST, MX, INV, b1, F1, 1);

  // layer 2: F1[50000,512] @ W2[512,40]  (mfma with zero-padded B, f32 C out)
  convert_BT2<<<(128*512+255)/256, 256, 0, stream>>>(W2, BT2h, BT2l);
  mfma_gemm<<<dim3(1, mt), 256, 0, stream>>>(F1, BT2h, BT2l, H2v, nullptr,
                                             nullptr, nullptr, nullptr, nullptr, N_NODES, 512, 40);
  attn_coef2_kernel<<<(N_NODES*64+255)/256, 256, 0, stream>>>(H2v, as2, ad2, ASRC2, ADST2);
  aggregate2_kernel<<<N_NODES, 64, 0, stream>>>(H2v, offsets, ssrc, ASRC2, ADST2, b2, out);
}

// Round 5
// 1169.798 us; speedup vs baseline: 1.1214x; 1.1214x over previous
//
#include <hip/hip_runtime.h>
#include <hip/hip_bf16.h>
#include <math.h>

#define N_NODES 50000
#define N_EDGES 800000
#define TOT_EDGES (N_EDGES + N_NODES)
#define NEG_SLOPE 0.2f
#define M_PAD 50048
#define N_CHUNKS ((N_NODES + 1023) / 1024)

typedef __attribute__((ext_vector_type(8))) short bf16x8;
typedef __attribute__((ext_vector_type(4))) float f32x4;

__device__ __forceinline__ unsigned short f2bf(float f){
  union { float f; unsigned u; } x; x.f = f;
  unsigned r = x.u + 0x7FFF + ((x.u >> 16) & 1);
  return (unsigned short)(r >> 16);
}
__device__ __forceinline__ float bf2f(unsigned short h){
  union { unsigned u; float f; } x; x.u = ((unsigned)h) << 16;
  return x.f;
}
__device__ __forceinline__ void gl_lds16(const void* g, void* l){
  __builtin_amdgcn_global_load_lds(
    (const __attribute__((address_space(1))) unsigned int*)g,
    (__attribute__((address_space(3))) unsigned int*)l, 16, 0, 0);
}

// ---------------- CSR build ----------------

__global__ void hist_kernel(const int* __restrict__ ei, int* __restrict__ counts){
  int e = blockIdx.x*256 + threadIdx.x;
  if (e >= TOT_EDGES) return;
  int d = (e < N_EDGES) ? ei[N_EDGES + e] : (e - N_EDGES);
  atomicAdd(&counts[d], 1);
}

__global__ void scan1_kernel(const int* __restrict__ counts, int* __restrict__ partial,
                             int* __restrict__ chunksum){
  __shared__ int sm[1024];
  int t = threadIdx.x;
  int idx = blockIdx.x*1024 + t;
  int v = (idx < N_NODES) ? counts[idx] : 0;
  sm[t] = v;
  __syncthreads();
  for (int off = 1; off < 1024; off <<= 1){
    int u = (t >= off) ? sm[t-off] : 0;
    __syncthreads();
    sm[t] += u;
    __syncthreads();
  }
  if (idx < N_NODES) partial[idx] = sm[t];
  if (t == 1023) chunksum[blockIdx.x] = sm[1023];
}

__global__ void scan2_kernel(const int* __restrict__ chunksum, int* __restrict__ carry){
  if (threadIdx.x == 0){
    int c = 0;
    for (int i = 0; i < N_CHUNKS; ++i){ carry[i] = c; c += chunksum[i]; }
  }
}

__global__ void scan3_kernel(const int* __restrict__ partial, const int* __restrict__ counts,
                             const int* __restrict__ carry, int* __restrict__ offsets,
                             int* __restrict__ cursor){
  int idx = blockIdx.x*256 + threadIdx.x;
  if (idx >= N_NODES) return;
  int inc = partial[idx] + carry[idx >> 10];
  offsets[idx+1] = inc;
  cursor[idx] = inc - counts[idx];
  if (idx == 0) offsets[0] = 0;
}

__global__ void scatter_kernel(const int* __restrict__ ei, int* __restrict__ cursor,
                               int* __restrict__ ssrc){
  int e = blockIdx.x*256 + threadIdx.x;
  if (e >= TOT_EDGES) return;
  int s, d;
  if (e < N_EDGES){ s = ei[e]; d = ei[N_EDGES+e]; } else { s = e - N_EDGES; d = s; }
  int pos = atomicAdd(&cursor[d], 1);
  ssrc[pos] = s;
}

// ---------------- weight split+transpose: BT[n][k] = B[k][n] as bf16 hi/lo ----------------

__global__ void convert_BT(const float* __restrict__ B, unsigned short* __restrict__ BTh,
                           unsigned short* __restrict__ BTl, int K, int N){
  int id = blockIdx.x*256 + threadIdx.x;
  if (id >= K*N) return;
  int n = id / K, k = id - n*K;
  float v = B[(size_t)k*N + n];
  unsigned short h = f2bf(v);
  unsigned short l = f2bf(v - bf2f(h));
  BTh[id] = h; BTl[id] = l;
}

// layer-2 weights [512,40] -> padded BT2 [128][512]
__global__ void convert_BT2(const float* __restrict__ B, unsigned short* __restrict__ BTh,
                            unsigned short* __restrict__ BTl){
  int id = blockIdx.x*256 + threadIdx.x;
  if (id >= 128*512) return;
  int n = id >> 9, k = id & 511;
  float v = (n < 40) ? B[(size_t)k*40 + n] : 0.f;
  unsigned short h = f2bf(v);
  unsigned short l = f2bf(v - bf2f(h));
  BTh[id] = h; BTl[id] = l;
}

// ---------------- split-bf16 MFMA GEMM + fused attn-coef + slice-blocked bf16 out ----------------
// 128x128 tile, BK=32, 4 waves, 3-term split (Ah*Bh + Al*Bh + Ah*Bl)

__global__ __launch_bounds__(256, 2) void mfma_gemm(
    const float* __restrict__ A, const unsigned short* __restrict__ BTh,
    const unsigned short* __restrict__ BTl, float* __restrict__ C,
    unsigned short* __restrict__ FbS,
    const float* __restrict__ att_s, const float* __restrict__ att_d,
    float* __restrict__ asrc, float* __restrict__ adst,
    int M, int K, int Nc)
{
  __shared__ unsigned short sAh[128*32];
  __shared__ unsigned short sAl[128*32];
  __shared__ unsigned short sBh[128*32];
  __shared__ unsigned short sBl[128*32];

  const int tid = threadIdx.x;
  const int lane = tid & 63;
  const int wid = tid >> 6;
  const int wr = wid >> 1, wc = wid & 1;
  const int bm = blockIdx.y * 128, bn = blockIdx.x * 128;
  const int lr = lane & 15, kg = lane >> 4;

  const float* aread[4];
  int awoff[4];
  #pragma unroll
  for (int i = 0; i < 4; ++i){
    int o = tid + i*256;
    int row = o >> 3, ch = o & 7;
    int gr = bm + row; if (gr > M-1) gr = M-1;
    aread[i] = A + (size_t)gr*K + ch*4;
    int sc = (ch >> 1) ^ ((row >> 1) & 3);
    awoff[i] = row*32 + sc*8 + (ch & 1)*4;
  }
  size_t bgoff[2];
  #pragma unroll
  for (int i = 0; i < 2; ++i){
    int o = tid + i*256;
    int row = o >> 2, ch = o & 3;
    int sc = ch ^ ((row >> 1) & 3);
    bgoff[i] = (size_t)(bn + row)*K + sc*8;
  }
  int aoff[4], boff[4];
  #pragma unroll
  for (int i = 0; i < 4; ++i){
    int row = wr*64 + i*16 + lr;
    aoff[i] = row*32 + (kg ^ ((row >> 1) & 3))*8;
    int col = wc*64 + i*16 + lr;
    boff[i] = col*32 + (kg ^ ((col >> 1) & 3))*8;
  }

  float4 areg[4];
  auto loadA = [&](int k0){
    #pragma unroll
    for (int i = 0; i < 4; ++i)
      areg[i] = *(const float4*)(aread[i] + k0);
  };
  auto writeA = [&](){
    #pragma unroll
    for (int i = 0; i < 4; ++i){
      float4 v = areg[i];
      ushort4 h, l;
      h.x = f2bf(v.x); l.x = f2bf(v.x - bf2f(h.x));
      h.y = f2bf(v.y); l.y = f2bf(v.y - bf2f(h.y));
      h.z = f2bf(v.z); l.z = f2bf(v.z - bf2f(h.z));
      h.w = f2bf(v.w); l.w = f2bf(v.w - bf2f(h.w));
      *(ushort4*)&sAh[awoff[i]] = h;
      *(ushort4*)&sAl[awoff[i]] = l;
    }
  };
  auto stageB = [&](int k0){
    #pragma unroll
    for (int i = 0; i < 2; ++i){
      gl_lds16(BTh + bgoff[i] + k0, &sBh[(tid + i*256)*8]);
      gl_lds16(BTl + bgoff[i] + k0, &sBl[(tid + i*256)*8]);
    }
  };

  f32x4 acc[4][4];
  #pragma unroll
  for (int i = 0; i < 4; ++i)
    #pragma unroll
    for (int j = 0; j < 4; ++j)
      acc[i][j] = (f32x4){0.f, 0.f, 0.f, 0.f};

  loadA(0); writeA(); stageB(0);
  __syncthreads();
  int k0 = 0;
  while (true){
    int kn = k0 + 32;
    if (kn < K) loadA(kn);
    bf16x8 ah[4], al[4], bh[4], bl[4];
    #pragma unroll
    for (int i = 0; i < 4; ++i){
      ah[i] = *(const bf16x8*)&sAh[aoff[i]];
      al[i] = *(const bf16x8*)&sAl[aoff[i]];
      bh[i] = *(const bf16x8*)&sBh[boff[i]];
      bl[i] = *(const bf16x8*)&sBl[boff[i]];
    }
    #pragma unroll
    for (int i = 0; i < 4; ++i)
      #pragma unroll
      for (int j = 0; j < 4; ++j){
        acc[i][j] = __builtin_amdgcn_mfma_f32_16x16x32_bf16(ah[i], bh[j], acc[i][j], 0, 0, 0);
        acc[i][j] = __builtin_amdgcn_mfma_f32_16x16x32_bf16(al[i], bh[j], acc[i][j], 0, 0, 0);
        acc[i][j] = __builtin_amdgcn_mfma_f32_16x16x32_bf16(ah[i], bl[j], acc[i][j], 0, 0, 0);
      }
    if (kn >= K) break;
    __syncthreads();
    writeA();
    stageB(kn);
    __syncthreads();
    k0 = kn;
  }

  // fused attention coefficients: each wave owns exactly one head's 64 cols
  if (att_s){
    int head = (bn >> 6) + wc;
    float ws_[4], wd_[4];
    #pragma unroll
    for (int j = 0; j < 4; ++j){
      ws_[j] = att_s[head*64 + j*16 + lr];
      wd_[j] = att_d[head*64 + j*16 + lr];
    }
    #pragma unroll
    for (int i = 0; i < 4; ++i){
      #pragma unroll
      for (int r = 0; r < 4; ++r){
        float vs = 0.f, vd = 0.f;
        #pragma unroll
        for (int j = 0; j < 4; ++j){
          vs += acc[i][j][r] * ws_[j];
          vd += acc[i][j][r] * wd_[j];
        }
        #pragma unroll
        for (int m = 1; m < 16; m <<= 1){
          vs += __shfl_xor(vs, m);
          vd += __shfl_xor(vd, m);
        }
        int gm = bm + wr*64 + i*16 + kg*4 + r;
        if ((lane & 15) == 0 && gm < M){
          asrc[gm*8 + head] = vs;
          adst[gm*8 + head] = vd;
        }
      }
    }
  }

  // epilogue: C/D layout col=lane&15, row=(lane>>4)*4+reg  [m89]
  #pragma unroll
  for (int i = 0; i < 4; ++i){
    int gm0 = bm + wr*64 + i*16 + kg*4;
    #pragma unroll
    for (int j = 0; j < 4; ++j){
      int gn = bn + wc*64 + j*16 + lr;
      int sl = gn >> 5, cc = gn & 31;
      #pragma unroll
      for (int r = 0; r < 4; ++r){
        int gm = gm0 + r;
        if (gm < M){
          if (C && gn < Nc) C[(size_t)gm*Nc + gn] = acc[i][j][r];
          if (FbS) FbS[(size_t)sl*(M_PAD*32) + (size_t)gm*32 + cc] = f2bf(acc[i][j][r]);
        }
      }
    }
  }
}

// ---------------- softmax stats + per-edge alpha (SoA [head][edge]) ----------------

__global__ __launch_bounds__(256) void softmax_stats(const int* __restrict__ offsets,
    const int* __restrict__ ssrc, const float* __restrict__ asrc,
    const float* __restrict__ adst, float* __restrict__ ALPHA){
  int w = threadIdx.x >> 6;
  int lane = threadIdx.x & 63;
  int d = blockIdx.x*4 + w;
  if (d >= N_NODES) return;
  int h = lane & 7, grp = lane >> 3;
  int beg = offsets[d], end = offsets[d+1];
  float ad = adst[d*8+h];
  float pm = -1e30f;
  for (int i = beg+grp; i < end; i += 8){
    int s = ssrc[i];
    float e = asrc[s*8+h] + ad;
    e = (e > 0.f) ? e : NEG_SLOPE*e;
    pm = fmaxf(pm, e);
  }
  pm = fmaxf(pm, __shfl_xor(pm, 8));
  pm = fmaxf(pm, __shfl_xor(pm, 16));
  pm = fmaxf(pm, __shfl_xor(pm, 32));
  float ps = 0.f;
  for (int i = beg+grp; i < end; i += 8){
    int s = ssrc[i];
    float e = asrc[s*8+h] + ad;
    e = (e > 0.f) ? e : NEG_SLOPE*e;
    ps += __expf(e - pm);
  }
  ps += __shfl_xor(ps, 8);
  ps += __shfl_xor(ps, 16);
  ps += __shfl_xor(ps, 32);
  float iv = 1.f / ps;
  float* Ah = ALPHA + (size_t)h * TOT_EDGES;
  for (int i = beg+grp; i < end; i += 8){
    int s = ssrc[i];
    float e = asrc[s*8+h] + ad;
    e = (e > 0.f) ? e : NEG_SLOPE*e;
    __builtin_nontemporal_store(__expf(e - pm) * iv, &Ah[i]);
  }
}

// ---------------- XCD-pinned channel-sliced SpMM ----------------
// FbS layout [16][M_PAD][32ch]; slice = bid%8 (+8 second half) pins each 3.2MB
// slice to one XCD's L2 for its whole pass. ssrc/alpha are nt-streamed,
// OUT nt-stored, so the resident slice is never evicted.

__global__ __launch_bounds__(256) void spmm_kernel(const unsigned short* __restrict__ FbS,
    const int* __restrict__ offsets, const int* __restrict__ ssrc,
    const float* __restrict__ ALPHA,
    const float* __restrict__ bias, float* __restrict__ OUT, int do_relu){
  int bid = blockIdx.x;
  int half = (bid >= 25000) ? 1 : 0;
  int r = bid - half*25000;
  int slice = (r & 7) + half*8;
  int chunk = r >> 3;               // 0..3124
  int ln = threadIdx.x & 15;        // 16 lanes per dst, 2 ch each
  int g = threadIdx.x >> 4;         // 16 dst per block
  int d = chunk*16 + g;
  int h = slice >> 1;
  const unsigned short* Ft = FbS + (size_t)slice * (M_PAD*32);
  const float* Ah = ALPHA + (size_t)h * TOT_EDGES;
  int beg = offsets[d], end = offsets[d+1];
  float a0 = 0.f, a1 = 0.f;
  #pragma unroll 2
  for (int i = beg; i < end; ++i){
    int s = __builtin_nontemporal_load(&ssrc[i]);
    float al = __builtin_nontemporal_load(&Ah[i]);
    unsigned v = *(const unsigned*)&Ft[(size_t)s*32 + ln*2];
    union { unsigned u; float f; } lo, hi;
    lo.u = v << 16;
    hi.u = v & 0xffff0000u;
    a0 += al * lo.f;
    a1 += al * hi.f;
  }
  int c = slice*32 + ln*2;
  float o0 = a0 + bias[c], o1 = a1 + bias[c+1];
  if (do_relu){ o0 = fmaxf(o0, 0.f); o1 = fmaxf(o1, 0.f); }
  float* op = OUT + (size_t)d*512 + c;
  __builtin_nontemporal_store(o0, op);
  __builtin_nontemporal_store(o1, op+1);
}

// ---------------- layer 2: H=1 C=40 ----------------

__global__ void attn_coef2_kernel(const float* __restrict__ H2v, const float* __restrict__ as2,
                                  const float* __restrict__ ad2,
                                  float* __restrict__ asrc, float* __restrict__ adst){
  int gid = blockIdx.x*256 + threadIdx.x;
  int node = gid >> 6;
  int lane = threadIdx.x & 63;
  if (node >= N_NODES) return;
  float v = 0.f, ws = 0.f, wd = 0.f;
  if (lane < 40){ v = H2v[(size_t)node*40 + lane]; ws = as2[lane]; wd = ad2[lane]; }
  float vs = v*ws, vd = v*wd;
  #pragma unroll
  for (int off = 32; off > 0; off >>= 1){
    vs += __shfl_down(vs, off);
    vd += __shfl_down(vd, off);
  }
  if (lane == 0){ asrc[node] = vs; adst[node] = vd; }
}

__global__ __launch_bounds__(64) void aggregate2_kernel(const float* __restrict__ H2v,
    const int* __restrict__ offsets, const int* __restrict__ ssrc,
    const float* __restrict__ asrc, const float* __restrict__ adst,
    const float* __restrict__ bias, float* __restrict__ OUT){
  int d = blockIdx.x;
  int lane = threadIdx.x;
  int beg = offsets[d], end = offsets[d+1];
  int deg = end - beg;
  float ad = adst[d];
  float pm = -1e30f;
  for (int i = lane; i < deg; i += 64){
    int s = ssrc[beg+i];
    float e = asrc[s] + ad; e = (e>0.f)?e:NEG_SLOPE*e;
    pm = fmaxf(pm, e);
  }
  #pragma unroll
  for (int off = 32; off > 0; off >>= 1) pm = fmaxf(pm, __shfl_xor(pm, off));
  float ps = 0.f;
  for (int i = lane; i < deg; i += 64){
    int s = ssrc[beg+i];
    float e = asrc[s] + ad; e=(e>0.f)?e:NEG_SLOPE*e;
    ps += __expf(e - pm);
  }
  #pragma unroll
  for (int off = 32; off > 0; off >>= 1) ps += __shfl_xor(ps, off);
  float inv = 1.f/ps;
  __shared__ float alS[64];
  __shared__ int sS[64];
  float acc = 0.f;
  for (int i0 = 0; i0 < deg; i0 += 64){
    int nch = min(64, deg - i0);
    if (lane < nch){
      int s = ssrc[beg+i0+lane];
      float e = asrc[s]+ad; e=(e>0.f)?e:NEG_SLOPE*e;
      alS[lane] = __expf(e-pm)*inv;
      sS[lane] = s;
    }
    __syncthreads();
    for (int i = 0; i < nch; ++i){
      if (lane < 40) acc += alS[i] * H2v[(size_t)sS[i]*40 + lane];
    }
    __syncthreads();
  }
  float logit = (lane<40) ? (acc + bias[lane]) : -1e30f;
  float mm = logit;
  #pragma unroll
  for (int off = 32; off > 0; off >>= 1) mm = fmaxf(mm, __shfl_xor(mm, off));
  float ex = (lane<40) ? __expf(logit-mm) : 0.f;
  float ss = ex;
  #pragma unroll
  for (int off = 32; off > 0; off >>= 1) ss += __shfl_xor(ss, off);
  if (lane < 40) OUT[(size_t)d*40 + lane] = logit - mm - logf(ss);
}

// ---------------- launch ----------------

extern "C" void kernel_launch(void* const* d_in, const int* in_sizes, int n_in,
                              void* d_out, int out_size, void* d_ws, size_t ws_size,
                              hipStream_t stream){
  const float* x   = (const float*)d_in[0];
  const int*   ei  = (const int*)d_in[1];
  const float* W0  = (const float*)d_in[2];
  const float* as0 = (const float*)d_in[3];
  const float* ad0 = (const float*)d_in[4];
  const float* b0  = (const float*)d_in[5];
  const float* W1  = (const float*)d_in[6];
  const float* as1 = (const float*)d_in[7];
  const float* ad1 = (const float*)d_in[8];
  const float* b1  = (const float*)d_in[9];
  const float* W2  = (const float*)d_in[10];
  const float* as2 = (const float*)d_in[11];
  const float* ad2 = (const float*)d_in[12];
  const float* b2  = (const float*)d_in[13];
  float* out = (float*)d_out;

  char* p = (char*)d_ws;
  auto alloc = [&](size_t bytes)->void*{
    void* r = (void*)p; p += (bytes + 255) & ~(size_t)255; return r;
  };
  float* F1    = (float*)alloc((size_t)M_PAD*512*4);
  unsigned short* FbS = (unsigned short*)alloc((size_t)M_PAD*512*2);
  float* ASRC  = (float*)alloc((size_t)N_NODES*8*4);
  float* ADST  = (float*)alloc((size_t)N_NODES*8*4);
  float* ALPHA = (float*)alloc((size_t)8*TOT_EDGES*4);
  float* H2v   = (float*)alloc((size_t)N_NODES*40*4);
  float* ASRC2 = (float*)alloc((size_t)N_NODES*4);
  float* ADST2 = (float*)alloc((size_t)N_NODES*4);
  int* counts  = (int*)alloc((size_t)N_NODES*4);
  int* offsets = (int*)alloc((size_t)(N_NODES+1)*4);
  int* cursor  = (int*)alloc((size_t)N_NODES*4);
  int* ssrc    = (int*)alloc((size_t)TOT_EDGES*4);
  int* partial = (int*)alloc((size_t)N_NODES*4);
  int* chunksum= (int*)alloc(64*4);
  int* carry   = (int*)alloc(64*4);
  unsigned short* BTh  = (unsigned short*)alloc((size_t)512*512*2);
  unsigned short* BTl  = (unsigned short*)alloc((size_t)512*512*2);
  unsigned short* BT2h = (unsigned short*)alloc((size_t)128*512*2);
  unsigned short* BT2l = (unsigned short*)alloc((size_t)128*512*2);

  // CSR build (same graph for all 3 layers)
  hipMemsetAsync(counts, 0, (size_t)N_NODES*4, stream);
  hist_kernel<<<(TOT_EDGES+255)/256, 256, 0, stream>>>(ei, counts);
  scan1_kernel<<<N_CHUNKS, 1024, 0, stream>>>(counts, partial, chunksum);
  scan2_kernel<<<1, 64, 0, stream>>>(chunksum, carry);
  scan3_kernel<<<(N_NODES+255)/256, 256, 0, stream>>>(partial, counts, carry, offsets, cursor);
  scatter_kernel<<<(TOT_EDGES+255)/256, 256, 0, stream>>>(ei, cursor, ssrc);

  int mt = M_PAD / 128;   // 391
  int spmm_blocks = 2 * 8 * 3125;   // 2 halves x 8 slices x 3125 chunks (16 dst each)

  // layer 0: x[50000,128] @ W0[128,512]
  convert_BT<<<(128*512+255)/256, 256, 0, stream>>>(W0, BTh, BTl, 128, 512);
  mfma_gemm<<<dim3(4, mt), 256, 0, stream>>>(x, BTh, BTl, nullptr, FbS,
                                             as0, ad0, ASRC, ADST, N_NODES, 128, 512);
  softmax_stats<<<(N_NODES+3)/4, 256, 0, stream>>>(offsets, ssrc, ASRC, ADST, ALPHA);
  spmm_kernel<<<spmm_blocks, 256, 0, stream>>>(FbS, offsets, ssrc, ALPHA, b0, F1, 1);

  // layer 1: F1[50000,512] @ W1[512,512]
  convert_BT<<<(512*512+255)/256, 256, 0, stream>>>(W1, BTh, BTl, 512, 512);
  mfma_gemm<<<dim3(4, mt), 256, 0, stream>>>(F1, BTh, BTl, nullptr, FbS,
                                             as1, ad1, ASRC, ADST, N_NODES, 512, 512);
  softmax_stats<<<(N_NODES+3)/4, 256, 0, stream>>>(offsets, ssrc, ASRC, ADST, ALPHA);
  spmm_kernel<<<spmm_blocks, 256, 0, stream>>>(FbS, offsets, ssrc, ALPHA, b1, F1, 1);

  // layer 2: F1[50000,512] @ W2[512,40]  (mfma with zero-padded B, f32 C out)
  convert_BT2<<<(128*512+255)/256, 256, 0, stream>>>(W2, BT2h, BT2l);
  mfma_gemm<<<dim3(1, mt), 256, 0, stream>>>(F1, BT2h, BT2l, H2v, nullptr,
                                             nullptr, nullptr, nullptr, nullptr, N_NODES, 512, 40);
  attn_coef2_kernel<<<(N_NODES*64+255)/256, 256, 0, stream>>>(H2v, as2, ad2, ASRC2, ADST2);
  aggregate2_kernel<<<N_NODES, 64, 0, stream>>>(H2v, offsets, ssrc, ASRC2, ADST2, b2, out);
}

// Round 7
// 1116.440 us; speedup vs baseline: 1.1750x; 1.0478x over previous
//
#include <hip/hip_runtime.h>
#include <hip/hip_bf16.h>
#include <math.h>

#define N_NODES 50000
#define N_EDGES 800000
#define TOT_EDGES (N_EDGES + N_NODES)
#define NEG_SLOPE 0.2f
#define M_PAD 50048
#define N_CHUNKS ((N_NODES + 1023) / 1024)

typedef __attribute__((ext_vector_type(8))) short bf16x8;
typedef __attribute__((ext_vector_type(4))) float f32x4;
typedef __attribute__((ext_vector_type(2))) float f32x2;

__device__ __forceinline__ unsigned short f2bf(float f){
  union { float f; unsigned u; } x; x.f = f;
  unsigned r = x.u + 0x7FFF + ((x.u >> 16) & 1);
  return (unsigned short)(r >> 16);
}
__device__ __forceinline__ float bf2f(unsigned short h){
  union { unsigned u; float f; } x; x.u = ((unsigned)h) << 16;
  return x.f;
}
__device__ __forceinline__ void gl_lds16(const void* g, void* l){
  __builtin_amdgcn_global_load_lds(
    (const __attribute__((address_space(1))) unsigned int*)g,
    (__attribute__((address_space(3))) unsigned int*)l, 16, 0, 0);
}

// ---------------- CSR build ----------------

__global__ void hist_kernel(const int* __restrict__ ei, int* __restrict__ counts){
  int e = blockIdx.x*256 + threadIdx.x;
  if (e >= TOT_EDGES) return;
  int d = (e < N_EDGES) ? ei[N_EDGES + e] : (e - N_EDGES);
  atomicAdd(&counts[d], 1);
}

__global__ void scan1_kernel(const int* __restrict__ counts, int* __restrict__ partial,
                             int* __restrict__ chunksum){
  __shared__ int sm[1024];
  int t = threadIdx.x;
  int idx = blockIdx.x*1024 + t;
  int v = (idx < N_NODES) ? counts[idx] : 0;
  sm[t] = v;
  __syncthreads();
  for (int off = 1; off < 1024; off <<= 1){
    int u = (t >= off) ? sm[t-off] : 0;
    __syncthreads();
    sm[t] += u;
    __syncthreads();
  }
  if (idx < N_NODES) partial[idx] = sm[t];
  if (t == 1023) chunksum[blockIdx.x] = sm[1023];
}

__global__ void scan2_kernel(const int* __restrict__ chunksum, int* __restrict__ carry){
  if (threadIdx.x == 0){
    int c = 0;
    for (int i = 0; i < N_CHUNKS; ++i){ carry[i] = c; c += chunksum[i]; }
  }
}

__global__ void scan3_kernel(const int* __restrict__ partial, const int* __restrict__ counts,
                             const int* __restrict__ carry, int* __restrict__ offsets,
                             int* __restrict__ cursor){
  int idx = blockIdx.x*256 + threadIdx.x;
  if (idx >= N_NODES) return;
  int inc = partial[idx] + carry[idx >> 10];
  offsets[idx+1] = inc;
  cursor[idx] = inc - counts[idx];
  if (idx == 0) offsets[0] = 0;
}

__global__ void scatter_kernel(const int* __restrict__ ei, int* __restrict__ cursor,
                               int* __restrict__ ssrc){
  int e = blockIdx.x*256 + threadIdx.x;
  if (e >= TOT_EDGES) return;
  int s, d;
  if (e < N_EDGES){ s = ei[e]; d = ei[N_EDGES+e]; } else { s = e - N_EDGES; d = s; }
  int pos = atomicAdd(&cursor[d], 1);
  ssrc[pos] = s;
}

// ---------------- weight split+transpose: BT[n][k] = B[k][n] as bf16 hi/lo ----------------

__global__ void convert_BT(const float* __restrict__ B, unsigned short* __restrict__ BTh,
                           unsigned short* __restrict__ BTl, int K, int N){
  int id = blockIdx.x*256 + threadIdx.x;
  if (id >= K*N) return;
  int n = id / K, k = id - n*K;
  float v = B[(size_t)k*N + n];
  unsigned short h = f2bf(v);
  unsigned short l = f2bf(v - bf2f(h));
  BTh[id] = h; BTl[id] = l;
}

// layer-2 weights [512,40] -> padded BT2 [128][512]
__global__ void convert_BT2(const float* __restrict__ B, unsigned short* __restrict__ BTh,
                            unsigned short* __restrict__ BTl){
  int id = blockIdx.x*256 + threadIdx.x;
  if (id >= 128*512) return;
  int n = id >> 9, k = id & 511;
  float v = (n < 40) ? B[(size_t)k*40 + n] : 0.f;
  unsigned short h = f2bf(v);
  unsigned short l = f2bf(v - bf2f(h));
  BTh[id] = h; BTl[id] = l;
}

// ---------------- split-bf16 MFMA GEMM + fused attn-coef + slice-blocked bf16 out ----------------
// 128x128 tile, BK=32, 4 waves, 3-term split (Ah*Bh + Al*Bh + Ah*Bl)

__global__ __launch_bounds__(256, 2) void mfma_gemm(
    const float* __restrict__ A, const unsigned short* __restrict__ BTh,
    const unsigned short* __restrict__ BTl, float* __restrict__ C,
    unsigned short* __restrict__ FbS,
    const float* __restrict__ att_s, const float* __restrict__ att_d,
    float* __restrict__ asrc, float* __restrict__ adst,
    int M, int K, int Nc)
{
  __shared__ unsigned short sAh[128*32];
  __shared__ unsigned short sAl[128*32];
  __shared__ unsigned short sBh[128*32];
  __shared__ unsigned short sBl[128*32];

  const int tid = threadIdx.x;
  const int lane = tid & 63;
  const int wid = tid >> 6;
  const int wr = wid >> 1, wc = wid & 1;
  const int bm = blockIdx.y * 128, bn = blockIdx.x * 128;
  const int lr = lane & 15, kg = lane >> 4;

  const float* aread[4];
  int awoff[4];
  #pragma unroll
  for (int i = 0; i < 4; ++i){
    int o = tid + i*256;
    int row = o >> 3, ch = o & 7;
    int gr = bm + row; if (gr > M-1) gr = M-1;
    aread[i] = A + (size_t)gr*K + ch*4;
    int sc = (ch >> 1) ^ ((row >> 1) & 3);
    awoff[i] = row*32 + sc*8 + (ch & 1)*4;
  }
  size_t bgoff[2];
  #pragma unroll
  for (int i = 0; i < 2; ++i){
    int o = tid + i*256;
    int row = o >> 2, ch = o & 3;
    int sc = ch ^ ((row >> 1) & 3);
    bgoff[i] = (size_t)(bn + row)*K + sc*8;
  }
  int aoff[4], boff[4];
  #pragma unroll
  for (int i = 0; i < 4; ++i){
    int row = wr*64 + i*16 + lr;
    aoff[i] = row*32 + (kg ^ ((row >> 1) & 3))*8;
    int col = wc*64 + i*16 + lr;
    boff[i] = col*32 + (kg ^ ((col >> 1) & 3))*8;
  }

  float4 areg[4];
  auto loadA = [&](int k0){
    #pragma unroll
    for (int i = 0; i < 4; ++i)
      areg[i] = *(const float4*)(aread[i] + k0);
  };
  auto writeA = [&](){
    #pragma unroll
    for (int i = 0; i < 4; ++i){
      float4 v = areg[i];
      ushort4 h, l;
      h.x = f2bf(v.x); l.x = f2bf(v.x - bf2f(h.x));
      h.y = f2bf(v.y); l.y = f2bf(v.y - bf2f(h.y));
      h.z = f2bf(v.z); l.z = f2bf(v.z - bf2f(h.z));
      h.w = f2bf(v.w); l.w = f2bf(v.w - bf2f(h.w));
      *(ushort4*)&sAh[awoff[i]] = h;
      *(ushort4*)&sAl[awoff[i]] = l;
    }
  };
  auto stageB = [&](int k0){
    #pragma unroll
    for (int i = 0; i < 2; ++i){
      gl_lds16(BTh + bgoff[i] + k0, &sBh[(tid + i*256)*8]);
      gl_lds16(BTl + bgoff[i] + k0, &sBl[(tid + i*256)*8]);
    }
  };

  f32x4 acc[4][4];
  #pragma unroll
  for (int i = 0; i < 4; ++i)
    #pragma unroll
    for (int j = 0; j < 4; ++j)
      acc[i][j] = (f32x4){0.f, 0.f, 0.f, 0.f};

  loadA(0); writeA(); stageB(0);
  __syncthreads();
  int k0 = 0;
  while (true){
    int kn = k0 + 32;
    if (kn < K) loadA(kn);
    bf16x8 ah[4], al[4], bh[4], bl[4];
    #pragma unroll
    for (int i = 0; i < 4; ++i){
      ah[i] = *(const bf16x8*)&sAh[aoff[i]];
      al[i] = *(const bf16x8*)&sAl[aoff[i]];
      bh[i] = *(const bf16x8*)&sBh[boff[i]];
      bl[i] = *(const bf16x8*)&sBl[boff[i]];
    }
    #pragma unroll
    for (int i = 0; i < 4; ++i)
      #pragma unroll
      for (int j = 0; j < 4; ++j){
        acc[i][j] = __builtin_amdgcn_mfma_f32_16x16x32_bf16(ah[i], bh[j], acc[i][j], 0, 0, 0);
        acc[i][j] = __builtin_amdgcn_mfma_f32_16x16x32_bf16(al[i], bh[j], acc[i][j], 0, 0, 0);
        acc[i][j] = __builtin_amdgcn_mfma_f32_16x16x32_bf16(ah[i], bl[j], acc[i][j], 0, 0, 0);
      }
    if (kn >= K) break;
    __syncthreads();
    writeA();
    stageB(kn);
    __syncthreads();
    k0 = kn;
  }

  // fused attention coefficients: each wave owns exactly one head's 64 cols
  if (att_s){
    int head = (bn >> 6) + wc;
    float ws_[4], wd_[4];
    #pragma unroll
    for (int j = 0; j < 4; ++j){
      ws_[j] = att_s[head*64 + j*16 + lr];
      wd_[j] = att_d[head*64 + j*16 + lr];
    }
    #pragma unroll
    for (int i = 0; i < 4; ++i){
      #pragma unroll
      for (int r = 0; r < 4; ++r){
        float vs = 0.f, vd = 0.f;
        #pragma unroll
        for (int j = 0; j < 4; ++j){
          vs += acc[i][j][r] * ws_[j];
          vd += acc[i][j][r] * wd_[j];
        }
        #pragma unroll
        for (int m = 1; m < 16; m <<= 1){
          vs += __shfl_xor(vs, m);
          vd += __shfl_xor(vd, m);
        }
        int gm = bm + wr*64 + i*16 + kg*4 + r;
        if ((lane & 15) == 0 && gm < M){
          asrc[gm*8 + head] = vs;
          adst[gm*8 + head] = vd;
        }
      }
    }
  }

  // epilogue: C/D layout col=lane&15, row=(lane>>4)*4+reg  [m89]
  #pragma unroll
  for (int i = 0; i < 4; ++i){
    int gm0 = bm + wr*64 + i*16 + kg*4;
    #pragma unroll
    for (int j = 0; j < 4; ++j){
      int gn = bn + wc*64 + j*16 + lr;
      int sl = gn >> 5, cc = gn & 31;
      #pragma unroll
      for (int r = 0; r < 4; ++r){
        int gm = gm0 + r;
        if (gm < M){
          if (C && gn < Nc) C[(size_t)gm*Nc + gn] = acc[i][j][r];
          if (FbS) FbS[(size_t)sl*(M_PAD*32) + (size_t)gm*32 + cc] = f2bf(acc[i][j][r]);
        }
      }
    }
  }
}

// ---------------- softmax stats + packed (src,alpha) stream EA[h][edge] ----------------

__global__ __launch_bounds__(256) void softmax_stats(const int* __restrict__ offsets,
    const int* __restrict__ ssrc, const float* __restrict__ asrc,
    const float* __restrict__ adst, f32x2* __restrict__ EA){
  int w = threadIdx.x >> 6;
  int lane = threadIdx.x & 63;
  int d = blockIdx.x*4 + w;
  if (d >= N_NODES) return;
  int h = lane & 7, grp = lane >> 3;
  int beg = offsets[d], end = offsets[d+1];
  float ad = adst[d*8+h];
  float pm = -1e30f;
  for (int i = beg+grp; i < end; i += 8){
    int s = ssrc[i];
    float e = asrc[s*8+h] + ad;
    e = (e > 0.f) ? e : NEG_SLOPE*e;
    pm = fmaxf(pm, e);
  }
  pm = fmaxf(pm, __shfl_xor(pm, 8));
  pm = fmaxf(pm, __shfl_xor(pm, 16));
  pm = fmaxf(pm, __shfl_xor(pm, 32));
  float ps = 0.f;
  for (int i = beg+grp; i < end; i += 8){
    int s = ssrc[i];
    float e = asrc[s*8+h] + ad;
    e = (e > 0.f) ? e : NEG_SLOPE*e;
    ps += __expf(e - pm);
  }
  ps += __shfl_xor(ps, 8);
  ps += __shfl_xor(ps, 16);
  ps += __shfl_xor(ps, 32);
  float iv = 1.f / ps;
  f32x2* Eh = EA + (size_t)h * TOT_EDGES;
  for (int i = beg+grp; i < end; i += 8){
    int s = ssrc[i];
    float e = asrc[s*8+h] + ad;
    e = (e > 0.f) ? e : NEG_SLOPE*e;
    f32x2 pk;
    pk.x = __int_as_float(s);
    pk.y = __expf(e - pm) * iv;
    __builtin_nontemporal_store(pk, &Eh[i]);
  }
}

// ---------------- XCD-pinned channel-sliced SpMM, wave-per-dst ----------------
// FbS layout [16][M_PAD][32ch]; slice = bid%8 (+8 second half) pins each 3.2MB
// slice to one XCD's L2. One dst per wave: 8 edge-slots x 8 ch-lanes x 4ch
// => serial chain ~deg/8, ~16 gathers in flight per wave (latency fix, R5 post-mortem).

__global__ __launch_bounds__(256) void spmm_kernel(const unsigned short* __restrict__ FbS,
    const int* __restrict__ offsets, const f32x2* __restrict__ EA,
    const float* __restrict__ bias, float* __restrict__ OUT, int do_relu){
  int bid = blockIdx.x;
  int half = (bid >= 100000) ? 1 : 0;
  int r = bid - half*100000;
  int slice = (r & 7) + half*8;
  int chunk = r >> 3;               // 0..12499
  int lane = threadIdx.x & 63;
  int wid = threadIdx.x >> 6;
  int d = chunk*4 + wid;
  int ch = lane & 7;                // 8 ch-lanes, 4 ch each
  int slot = lane >> 3;             // 8 edge slots
  int h = slice >> 1;
  const unsigned short* Ft = FbS + (size_t)slice * (M_PAD*32);
  const f32x2* Eh = EA + (size_t)h * TOT_EDGES;
  int beg = offsets[d], end = offsets[d+1];
  float a0 = 0.f, a1 = 0.f, a2 = 0.f, a3 = 0.f;
  #pragma unroll 2
  for (int i = beg + slot; i < end; i += 8){
    f32x2 ea = __builtin_nontemporal_load(&Eh[i]);
    int s = __float_as_int(ea.x);
    float al = ea.y;
    uint2 v = *(const uint2*)&Ft[(size_t)s*32 + ch*4];
    union { unsigned u; float f; } c0, c1, c2, c3;
    c0.u = v.x << 16; c1.u = v.x & 0xffff0000u;
    c2.u = v.y << 16; c3.u = v.y & 0xffff0000u;
    a0 += al * c0.f;
    a1 += al * c1.f;
    a2 += al * c2.f;
    a3 += al * c3.f;
  }
  #pragma unroll
  for (int m = 8; m < 64; m <<= 1){
    a0 += __shfl_xor(a0, m);
    a1 += __shfl_xor(a1, m);
    a2 += __shfl_xor(a2, m);
    a3 += __shfl_xor(a3, m);
  }
  if (slot == 0){
    int c = slice*32 + ch*4;
    float4 bb = *(const float4*)&bias[c];
    f32x4 o;
    o.x = a0 + bb.x; o.y = a1 + bb.y; o.z = a2 + bb.z; o.w = a3 + bb.w;
    if (do_relu){
      o.x = fmaxf(o.x, 0.f); o.y = fmaxf(o.y, 0.f);
      o.z = fmaxf(o.z, 0.f); o.w = fmaxf(o.w, 0.f);
    }
    __builtin_nontemporal_store(o, (f32x4*)(OUT + (size_t)d*512 + c));
  }
}

// ---------------- layer 2: H=1 C=40 ----------------

__global__ void attn_coef2_kernel(const float* __restrict__ H2v, const float* __restrict__ as2,
                                  const float* __restrict__ ad2,
                                  float* __restrict__ asrc, float* __restrict__ adst){
  int gid = blockIdx.x*256 + threadIdx.x;
  int node = gid >> 6;
  int lane = threadIdx.x & 63;
  if (node >= N_NODES) return;
  float v = 0.f, ws = 0.f, wd = 0.f;
  if (lane < 40){ v = H2v[(size_t)node*40 + lane]; ws = as2[lane]; wd = ad2[lane]; }
  float vs = v*ws, vd = v*wd;
  #pragma unroll
  for (int off = 32; off > 0; off >>= 1){
    vs += __shfl_down(vs, off);
    vd += __shfl_down(vd, off);
  }
  if (lane == 0){ asrc[node] = vs; adst[node] = vd; }
}

__global__ __launch_bounds__(64) void aggregate2_kernel(const float* __restrict__ H2v,
    const int* __restrict__ offsets, const int* __restrict__ ssrc,
    const float* __restrict__ asrc, const float* __restrict__ adst,
    const float* __restrict__ bias, float* __restrict__ OUT){
  int d = blockIdx.x;
  int lane = threadIdx.x;
  int beg = offsets[d], end = offsets[d+1];
  int deg = end - beg;
  float ad = adst[d];
  float pm = -1e30f;
  for (int i = lane; i < deg; i += 64){
    int s = ssrc[beg+i];
    float e = asrc[s] + ad; e = (e>0.f)?e:NEG_SLOPE*e;
    pm = fmaxf(pm, e);
  }
  #pragma unroll
  for (int off = 32; off > 0; off >>= 1) pm = fmaxf(pm, __shfl_xor(pm, off));
  float ps = 0.f;
  for (int i = lane; i < deg; i += 64){
    int s = ssrc[beg+i];
    float e = asrc[s] + ad; e=(e>0.f)?e:NEG_SLOPE*e;
    ps += __expf(e - pm);
  }
  #pragma unroll
  for (int off = 32; off > 0; off >>= 1) ps += __shfl_xor(ps, off);
  float inv = 1.f/ps;
  __shared__ float alS[64];
  __shared__ int sS[64];
  float acc = 0.f;
  for (int i0 = 0; i0 < deg; i0 += 64){
    int nch = min(64, deg - i0);
    if (lane < nch){
      int s = ssrc[beg+i0+lane];
      float e = asrc[s]+ad; e=(e>0.f)?e:NEG_SLOPE*e;
      alS[lane] = __expf(e-pm)*inv;
      sS[lane] = s;
    }
    __syncthreads();
    for (int i = 0; i < nch; ++i){
      if (lane < 40) acc += alS[i] * H2v[(size_t)sS[i]*40 + lane];
    }
    __syncthreads();
  }
  float logit = (lane<40) ? (acc + bias[lane]) : -1e30f;
  float mm = logit;
  #pragma unroll
  for (int off = 32; off > 0; off >>= 1) mm = fmaxf(mm, __shfl_xor(mm, off));
  float ex = (lane<40) ? __expf(logit-mm) : 0.f;
  float ss = ex;
  #pragma unroll
  for (int off = 32; off > 0; off >>= 1) ss += __shfl_xor(ss, off);
  if (lane < 40) OUT[(size_t)d*40 + lane] = logit - mm - logf(ss);
}

// ---------------- launch ----------------

extern "C" void kernel_launch(void* const* d_in, const int* in_sizes, int n_in,
                              void* d_out, int out_size, void* d_ws, size_t ws_size,
                              hipStream_t stream){
  const float* x   = (const float*)d_in[0];
  const int*   ei  = (const int*)d_in[1];
  const float* W0  = (const float*)d_in[2];
  const float* as0 = (const float*)d_in[3];
  const float* ad0 = (const float*)d_in[4];
  const float* b0  = (const float*)d_in[5];
  const float* W1  = (const float*)d_in[6];
  const float* as1 = (const float*)d_in[7];
  const float* ad1 = (const float*)d_in[8];
  const float* b1  = (const float*)d_in[9];
  const float* W2  = (const float*)d_in[10];
  const float* as2 = (const float*)d_in[11];
  const float* ad2 = (const float*)d_in[12];
  const float* b2  = (const float*)d_in[13];
  float* out = (float*)d_out;

  char* p = (char*)d_ws;
  auto alloc = [&](size_t bytes)->void*{
    void* r = (void*)p; p += (bytes + 255) & ~(size_t)255; return r;
  };
  float* F1    = (float*)alloc((size_t)M_PAD*512*4);
  unsigned short* FbS = (unsigned short*)alloc((size_t)M_PAD*512*2);
  float* ASRC  = (float*)alloc((size_t)N_NODES*8*4);
  float* ADST  = (float*)alloc((size_t)N_NODES*8*4);
  f32x2* EA    = (f32x2*)alloc((size_t)8*TOT_EDGES*8);
  float* H2v   = (float*)alloc((size_t)N_NODES*40*4);
  float* ASRC2 = (float*)alloc((size_t)N_NODES*4);
  float* ADST2 = (float*)alloc((size_t)N_NODES*4);
  int* counts  = (int*)alloc((size_t)N_NODES*4);
  int* offsets = (int*)alloc((size_t)(N_NODES+1)*4);
  int* cursor  = (int*)alloc((size_t)N_NODES*4);
  int* ssrc    = (int*)alloc((size_t)TOT_EDGES*4);
  int* partial = (int*)alloc((size_t)N_NODES*4);
  int* chunksum= (int*)alloc(64*4);
  int* carry   = (int*)alloc(64*4);
  unsigned short* BTh  = (unsigned short*)alloc((size_t)512*512*2);
  unsigned short* BTl  = (unsigned short*)alloc((size_t)512*512*2);
  unsigned short* BT2h = (unsigned short*)alloc((size_t)128*512*2);
  unsigned short* BT2l = (unsigned short*)alloc((size_t)128*512*2);

  // CSR build (same graph for all 3 layers)
  hipMemsetAsync(counts, 0, (size_t)N_NODES*4, stream);
  hist_kernel<<<(TOT_EDGES+255)/256, 256, 0, stream>>>(ei, counts);
  scan1_kernel<<<N_CHUNKS, 1024, 0, stream>>>(counts, partial, chunksum);
  scan2_kernel<<<1, 64, 0, stream>>>(chunksum, carry);
  scan3_kernel<<<(N_NODES+255)/256, 256, 0, stream>>>(partial, counts, carry, offsets, cursor);
  scatter_kernel<<<(TOT_EDGES+255)/256, 256, 0, stream>>>(ei, cursor, ssrc);

  int mt = M_PAD / 128;   // 391
  int spmm_blocks = 2 * 8 * 12500;  // 2 halves x 8 slices x 12500 chunks (4 dst/block)

  // layer 0: x[50000,128] @ W0[128,512]
  convert_BT<<<(128*512+255)/256, 256, 0, stream>>>(W0, BTh, BTl, 128, 512);
  mfma_gemm<<<dim3(4, mt), 256, 0, stream>>>(x, BTh, BTl, nullptr, FbS,
                                             as0, ad0, ASRC, ADST, N_NODES, 128, 512);
  softmax_stats<<<(N_NODES+3)/4, 256, 0, stream>>>(offsets, ssrc, ASRC, ADST, EA);
  spmm_kernel<<<spmm_blocks, 256, 0, stream>>>(FbS, offsets, EA, b0, F1, 1);

  // layer 1: F1[50000,512] @ W1[512,512]
  convert_BT<<<(512*512+255)/256, 256, 0, stream>>>(W1, BTh, BTl, 512, 512);
  mfma_gemm<<<dim3(4, mt), 256, 0, stream>>>(F1, BTh, BTl, nullptr, FbS,
                                             as1, ad1, ASRC, ADST, N_NODES, 512, 512);
  softmax_stats<<<(N_NODES+3)/4, 256, 0, stream>>>(offsets, ssrc, ASRC, ADST, EA);
  spmm_kernel<<<spmm_blocks, 256, 0, stream>>>(FbS, offsets, EA, b1, F1, 1);

  // layer 2: F1[50000,512] @ W2[512,40]  (mfma with zero-padded B, f32 C out)
  convert_BT2<<<(128*512+255)/256, 256, 0, stream>>>(W2, BT2h, BT2l);
  mfma_gemm<<<dim3(1, mt), 256, 0, stream>>>(F1, BT2h, BT2l, H2v, nullptr,
                                             nullptr, nullptr, nullptr, nullptr, N_NODES, 512, 40);
  attn_coef2_kernel<<<(N_NODES*64+255)/256, 256, 0, stream>>>(H2v, as2, ad2, ASRC2, ADST2);
  aggregate2_kernel<<<N_NODES, 64, 0, stream>>>(H2v, offsets, ssrc, ASRC2, ADST2, b2, out);
}

// Round 8
// 768.854 us; speedup vs baseline: 1.7062x; 1.4521x over previous
//
#include <hip/hip_runtime.h>
#include <hip/hip_bf16.h>
#include <hip/hip_fp16.h>
#include <math.h>

#define N_NODES 50000
#define N_EDGES 800000
#define TOT_EDGES (N_EDGES + N_NODES)
#define NEG_SLOPE 0.2f
#define M_PAD 50048
#define N_CHUNKS ((N_NODES + 1023) / 1024)

typedef __attribute__((ext_vector_type(8))) short bf16x8;
typedef __attribute__((ext_vector_type(4))) float f32x4;

__device__ __forceinline__ unsigned short f2bf(float f){
  union { float f; unsigned u; } x; x.f = f;
  unsigned r = x.u + 0x7FFF + ((x.u >> 16) & 1);
  return (unsigned short)(r >> 16);
}
__device__ __forceinline__ float bf2f(unsigned short h){
  union { unsigned u; float f; } x; x.u = ((unsigned)h) << 16;
  return x.f;
}
__device__ __forceinline__ void gl_lds16(const void* g, void* l){
  __builtin_amdgcn_global_load_lds(
    (const __attribute__((address_space(1))) unsigned int*)g,
    (__attribute__((address_space(3))) unsigned int*)l, 16, 0, 0);
}

// ---------------- CSR build ----------------

__global__ void hist_kernel(const int* __restrict__ ei, int* __restrict__ counts){
  int e = blockIdx.x*256 + threadIdx.x;
  if (e >= TOT_EDGES) return;
  int d = (e < N_EDGES) ? ei[N_EDGES + e] : (e - N_EDGES);
  atomicAdd(&counts[d], 1);
}

__global__ void scan1_kernel(const int* __restrict__ counts, int* __restrict__ partial,
                             int* __restrict__ chunksum){
  __shared__ int sm[1024];
  int t = threadIdx.x;
  int idx = blockIdx.x*1024 + t;
  int v = (idx < N_NODES) ? counts[idx] : 0;
  sm[t] = v;
  __syncthreads();
  for (int off = 1; off < 1024; off <<= 1){
    int u = (t >= off) ? sm[t-off] : 0;
    __syncthreads();
    sm[t] += u;
    __syncthreads();
  }
  if (idx < N_NODES) partial[idx] = sm[t];
  if (t == 1023) chunksum[blockIdx.x] = sm[1023];
}

__global__ void scan2_kernel(const int* __restrict__ chunksum, int* __restrict__ carry){
  if (threadIdx.x == 0){
    int c = 0;
    for (int i = 0; i < N_CHUNKS; ++i){ carry[i] = c; c += chunksum[i]; }
  }
}

__global__ void scan3_kernel(const int* __restrict__ partial, const int* __restrict__ counts,
                             const int* __restrict__ carry, int* __restrict__ offsets,
                             int* __restrict__ cursor){
  int idx = blockIdx.x*256 + threadIdx.x;
  if (idx >= N_NODES) return;
  int inc = partial[idx] + carry[idx >> 10];
  offsets[idx+1] = inc;
  cursor[idx] = inc - counts[idx];
  if (idx == 0) offsets[0] = 0;
}

__global__ void scatter_kernel(const int* __restrict__ ei, int* __restrict__ cursor,
                               int* __restrict__ ssrc){
  int e = blockIdx.x*256 + threadIdx.x;
  if (e >= TOT_EDGES) return;
  int s, d;
  if (e < N_EDGES){ s = ei[e]; d = ei[N_EDGES+e]; } else { s = e - N_EDGES; d = s; }
  int pos = atomicAdd(&cursor[d], 1);
  ssrc[pos] = s;
}

// ---------------- weight split+transpose: BT[n][k] = B[k][n] as bf16 hi/lo ----------------

__global__ void convert_BT(const float* __restrict__ B, unsigned short* __restrict__ BTh,
                           unsigned short* __restrict__ BTl, int K, int N){
  int id = blockIdx.x*256 + threadIdx.x;
  if (id >= K*N) return;
  int n = id / K, k = id - n*K;
  float v = B[(size_t)k*N + n];
  unsigned short h = f2bf(v);
  unsigned short l = f2bf(v - bf2f(h));
  BTh[id] = h; BTl[id] = l;
}

// layer-2 weights [512,40] -> padded BT2 [128][512]
__global__ void convert_BT2(const float* __restrict__ B, unsigned short* __restrict__ BTh,
                            unsigned short* __restrict__ BTl){
  int id = blockIdx.x*256 + threadIdx.x;
  if (id >= 128*512) return;
  int n = id >> 9, k = id & 511;
  float v = (n < 40) ? B[(size_t)k*40 + n] : 0.f;
  unsigned short h = f2bf(v);
  unsigned short l = f2bf(v - bf2f(h));
  BTh[id] = h; BTl[id] = l;
}

// ---------------- split-bf16 MFMA GEMM + fused attn-coef + slice-blocked bf16 out ----------------
// 128x128 tile, BK=32, 4 waves, 3-term split (Ah*Bh + Al*Bh + Ah*Bl)

__global__ __launch_bounds__(256, 2) void mfma_gemm(
    const float* __restrict__ A, const unsigned short* __restrict__ BTh,
    const unsigned short* __restrict__ BTl, float* __restrict__ C,
    unsigned short* __restrict__ FbS,
    const float* __restrict__ att_s, const float* __restrict__ att_d,
    float* __restrict__ asrc, float* __restrict__ adst,
    int M, int K, int Nc)
{
  __shared__ unsigned short sAh[128*32];
  __shared__ unsigned short sAl[128*32];
  __shared__ unsigned short sBh[128*32];
  __shared__ unsigned short sBl[128*32];

  const int tid = threadIdx.x;
  const int lane = tid & 63;
  const int wid = tid >> 6;
  const int wr = wid >> 1, wc = wid & 1;
  const int bm = blockIdx.y * 128, bn = blockIdx.x * 128;
  const int lr = lane & 15, kg = lane >> 4;

  const float* aread[4];
  int awoff[4];
  #pragma unroll
  for (int i = 0; i < 4; ++i){
    int o = tid + i*256;
    int row = o >> 3, ch = o & 7;
    int gr = bm + row; if (gr > M-1) gr = M-1;
    aread[i] = A + (size_t)gr*K + ch*4;
    int sc = (ch >> 1) ^ ((row >> 1) & 3);
    awoff[i] = row*32 + sc*8 + (ch & 1)*4;
  }
  size_t bgoff[2];
  #pragma unroll
  for (int i = 0; i < 2; ++i){
    int o = tid + i*256;
    int row = o >> 2, ch = o & 3;
    int sc = ch ^ ((row >> 1) & 3);
    bgoff[i] = (size_t)(bn + row)*K + sc*8;
  }
  int aoff[4], boff[4];
  #pragma unroll
  for (int i = 0; i < 4; ++i){
    int row = wr*64 + i*16 + lr;
    aoff[i] = row*32 + (kg ^ ((row >> 1) & 3))*8;
    int col = wc*64 + i*16 + lr;
    boff[i] = col*32 + (kg ^ ((col >> 1) & 3))*8;
  }

  float4 areg[4];
  auto loadA = [&](int k0){
    #pragma unroll
    for (int i = 0; i < 4; ++i)
      areg[i] = *(const float4*)(aread[i] + k0);
  };
  auto writeA = [&](){
    #pragma unroll
    for (int i = 0; i < 4; ++i){
      float4 v = areg[i];
      ushort4 h, l;
      h.x = f2bf(v.x); l.x = f2bf(v.x - bf2f(h.x));
      h.y = f2bf(v.y); l.y = f2bf(v.y - bf2f(h.y));
      h.z = f2bf(v.z); l.z = f2bf(v.z - bf2f(h.z));
      h.w = f2bf(v.w); l.w = f2bf(v.w - bf2f(h.w));
      *(ushort4*)&sAh[awoff[i]] = h;
      *(ushort4*)&sAl[awoff[i]] = l;
    }
  };
  auto stageB = [&](int k0){
    #pragma unroll
    for (int i = 0; i < 2; ++i){
      gl_lds16(BTh + bgoff[i] + k0, &sBh[(tid + i*256)*8]);
      gl_lds16(BTl + bgoff[i] + k0, &sBl[(tid + i*256)*8]);
    }
  };

  f32x4 acc[4][4];
  #pragma unroll
  for (int i = 0; i < 4; ++i)
    #pragma unroll
    for (int j = 0; j < 4; ++j)
      acc[i][j] = (f32x4){0.f, 0.f, 0.f, 0.f};

  loadA(0); writeA(); stageB(0);
  __syncthreads();
  int k0 = 0;
  while (true){
    int kn = k0 + 32;
    if (kn < K) loadA(kn);
    bf16x8 ah[4], al[4], bh[4], bl[4];
    #pragma unroll
    for (int i = 0; i < 4; ++i){
      ah[i] = *(const bf16x8*)&sAh[aoff[i]];
      al[i] = *(const bf16x8*)&sAl[aoff[i]];
      bh[i] = *(const bf16x8*)&sBh[boff[i]];
      bl[i] = *(const bf16x8*)&sBl[boff[i]];
    }
    #pragma unroll
    for (int i = 0; i < 4; ++i)
      #pragma unroll
      for (int j = 0; j < 4; ++j){
        acc[i][j] = __builtin_amdgcn_mfma_f32_16x16x32_bf16(ah[i], bh[j], acc[i][j], 0, 0, 0);
        acc[i][j] = __builtin_amdgcn_mfma_f32_16x16x32_bf16(al[i], bh[j], acc[i][j], 0, 0, 0);
        acc[i][j] = __builtin_amdgcn_mfma_f32_16x16x32_bf16(ah[i], bl[j], acc[i][j], 0, 0, 0);
      }
    if (kn >= K) break;
    __syncthreads();
    writeA();
    stageB(kn);
    __syncthreads();
    k0 = kn;
  }

  // fused attention coefficients: each wave owns exactly one head's 64 cols
  if (att_s){
    int head = (bn >> 6) + wc;
    float ws_[4], wd_[4];
    #pragma unroll
    for (int j = 0; j < 4; ++j){
      ws_[j] = att_s[head*64 + j*16 + lr];
      wd_[j] = att_d[head*64 + j*16 + lr];
    }
    #pragma unroll
    for (int i = 0; i < 4; ++i){
      #pragma unroll
      for (int r = 0; r < 4; ++r){
        float vs = 0.f, vd = 0.f;
        #pragma unroll
        for (int j = 0; j < 4; ++j){
          vs += acc[i][j][r] * ws_[j];
          vd += acc[i][j][r] * wd_[j];
        }
        #pragma unroll
        for (int m = 1; m < 16; m <<= 1){
          vs += __shfl_xor(vs, m);
          vd += __shfl_xor(vd, m);
        }
        int gm = bm + wr*64 + i*16 + kg*4 + r;
        if ((lane & 15) == 0 && gm < M){
          asrc[gm*8 + head] = vs;
          adst[gm*8 + head] = vd;
        }
      }
    }
  }

  // epilogue: C/D layout col=lane&15, row=(lane>>4)*4+reg  [m89]
  #pragma unroll
  for (int i = 0; i < 4; ++i){
    int gm0 = bm + wr*64 + i*16 + kg*4;
    #pragma unroll
    for (int j = 0; j < 4; ++j){
      int gn = bn + wc*64 + j*16 + lr;
      int sl = gn >> 5, cc = gn & 31;
      #pragma unroll
      for (int r = 0; r < 4; ++r){
        int gm = gm0 + r;
        if (gm < M){
          if (C && gn < Nc) C[(size_t)gm*Nc + gn] = acc[i][j][r];
          if (FbS) FbS[(size_t)sl*(M_PAD*32) + (size_t)gm*32 + cc] = f2bf(acc[i][j][r]);
        }
      }
    }
  }
}

// ---------------- softmax stats + packed u32 (src | f16(alpha)<<16) stream EA[h][edge] ----------------

__global__ __launch_bounds__(256) void softmax_stats(const int* __restrict__ offsets,
    const int* __restrict__ ssrc, const float* __restrict__ asrc,
    const float* __restrict__ adst, unsigned* __restrict__ EA){
  int w = threadIdx.x >> 6;
  int lane = threadIdx.x & 63;
  int d = blockIdx.x*4 + w;
  if (d >= N_NODES) return;
  int h = lane & 7, grp = lane >> 3;
  int beg = offsets[d], end = offsets[d+1];
  float ad = adst[d*8+h];
  float pm = -1e30f;
  for (int i = beg+grp; i < end; i += 8){
    int s = ssrc[i];
    float e = asrc[s*8+h] + ad;
    e = (e > 0.f) ? e : NEG_SLOPE*e;
    pm = fmaxf(pm, e);
  }
  pm = fmaxf(pm, __shfl_xor(pm, 8));
  pm = fmaxf(pm, __shfl_xor(pm, 16));
  pm = fmaxf(pm, __shfl_xor(pm, 32));
  float ps = 0.f;
  for (int i = beg+grp; i < end; i += 8){
    int s = ssrc[i];
    float e = asrc[s*8+h] + ad;
    e = (e > 0.f) ? e : NEG_SLOPE*e;
    ps += __expf(e - pm);
  }
  ps += __shfl_xor(ps, 8);
  ps += __shfl_xor(ps, 16);
  ps += __shfl_xor(ps, 32);
  float iv = 1.f / ps;
  unsigned* Eh = EA + (size_t)h * TOT_EDGES;
  for (int i = beg+grp; i < end; i += 8){
    int s = ssrc[i];
    float e = asrc[s*8+h] + ad;
    e = (e > 0.f) ? e : NEG_SLOPE*e;
    float al = __expf(e - pm) * iv;
    union { __half hh; unsigned short u; } cv; cv.hh = __float2half(al);
    unsigned pk = (unsigned)s | ((unsigned)cv.u << 16);
    __builtin_nontemporal_store(pk, &Eh[i]);
  }
}

// ---------------- XCD-pinned channel-sliced SpMM, 4-dst-per-wave ----------------
// FbS layout [16][M_PAD][32ch]; slice = bid%8 (+8 second half) pins each 3.2MB
// slice to one XCD's L2. Wave = 4 dst x 4 edge-slots x 4 ch-lanes (uint4 = 8ch each):
// fixed costs amortized over 4 dst, 4 independent dep-chains per wave (R7 post-mortem).

__global__ __launch_bounds__(256) void spmm_kernel(const unsigned short* __restrict__ FbS,
    const int* __restrict__ offsets, const unsigned* __restrict__ EA,
    const float* __restrict__ bias, float* __restrict__ OUT, int do_relu){
  int bid = blockIdx.x;
  int half = (bid >= 25000) ? 1 : 0;
  int r = bid - half*25000;
  int slice = (r & 7) + half*8;
  int chunk = r >> 3;               // 0..3124
  int lane = threadIdx.x & 63;
  int wid = threadIdx.x >> 6;
  int dsub = lane >> 4;             // 4 dst per wave
  int slot = (lane >> 2) & 3;       // 4 edge slots
  int ch = lane & 3;                // 4 ch-lanes x 8 ch
  int d = chunk*16 + wid*4 + dsub;
  int h = slice >> 1;
  const unsigned short* Ft = FbS + (size_t)slice * (M_PAD*32);
  const unsigned* Eh = EA + (size_t)h * TOT_EDGES;
  int beg = offsets[d], end = offsets[d+1];
  float a0=0.f,a1=0.f,a2=0.f,a3=0.f,a4=0.f,a5=0.f,a6=0.f,a7=0.f;
  #pragma unroll 2
  for (int i = beg + slot; i < end; i += 4){
    unsigned ea = __builtin_nontemporal_load(&Eh[i]);
    int s = ea & 0xFFFF;
    union { unsigned short u; __half hh; } dv; dv.u = (unsigned short)(ea >> 16);
    float al = __half2float(dv.hh);
    uint4 v = *(const uint4*)&Ft[(size_t)s*32 + ch*8];
    union { unsigned q; float f; } lo, hi;
    lo.q = v.x << 16; hi.q = v.x & 0xffff0000u; a0 += al*lo.f; a1 += al*hi.f;
    lo.q = v.y << 16; hi.q = v.y & 0xffff0000u; a2 += al*lo.f; a3 += al*hi.f;
    lo.q = v.z << 16; hi.q = v.z & 0xffff0000u; a4 += al*lo.f; a5 += al*hi.f;
    lo.q = v.w << 16; hi.q = v.w & 0xffff0000u; a6 += al*lo.f; a7 += al*hi.f;
  }
  // reduce over slot (lane bits 2-3)
  a0 += __shfl_xor(a0, 4); a0 += __shfl_xor(a0, 8);
  a1 += __shfl_xor(a1, 4); a1 += __shfl_xor(a1, 8);
  a2 += __shfl_xor(a2, 4); a2 += __shfl_xor(a2, 8);
  a3 += __shfl_xor(a3, 4); a3 += __shfl_xor(a3, 8);
  a4 += __shfl_xor(a4, 4); a4 += __shfl_xor(a4, 8);
  a5 += __shfl_xor(a5, 4); a5 += __shfl_xor(a5, 8);
  a6 += __shfl_xor(a6, 4); a6 += __shfl_xor(a6, 8);
  a7 += __shfl_xor(a7, 4); a7 += __shfl_xor(a7, 8);
  if (slot == 0){
    int c = slice*32 + ch*8;
    float4 b0v = *(const float4*)&bias[c];
    float4 b1v = *(const float4*)&bias[c+4];
    f32x4 o0, o1;
    o0.x = a0 + b0v.x; o0.y = a1 + b0v.y; o0.z = a2 + b0v.z; o0.w = a3 + b0v.w;
    o1.x = a4 + b1v.x; o1.y = a5 + b1v.y; o1.z = a6 + b1v.z; o1.w = a7 + b1v.w;
    if (do_relu){
      o0.x = fmaxf(o0.x, 0.f); o0.y = fmaxf(o0.y, 0.f);
      o0.z = fmaxf(o0.z, 0.f); o0.w = fmaxf(o0.w, 0.f);
      o1.x = fmaxf(o1.x, 0.f); o1.y = fmaxf(o1.y, 0.f);
      o1.z = fmaxf(o1.z, 0.f); o1.w = fmaxf(o1.w, 0.f);
    }
    float* op = OUT + (size_t)d*512 + c;
    __builtin_nontemporal_store(o0, (f32x4*)op);
    __builtin_nontemporal_store(o1, (f32x4*)(op+4));
  }
}

// ---------------- layer 2: H=1 C=40 ----------------

__global__ void attn_coef2_kernel(const float* __restrict__ H2v, const float* __restrict__ as2,
                                  const float* __restrict__ ad2,
                                  float* __restrict__ asrc, float* __restrict__ adst){
  int gid = blockIdx.x*256 + threadIdx.x;
  int node = gid >> 6;
  int lane = threadIdx.x & 63;
  if (node >= N_NODES) return;
  float v = 0.f, ws = 0.f, wd = 0.f;
  if (lane < 40){ v = H2v[(size_t)node*40 + lane]; ws = as2[lane]; wd = ad2[lane]; }
  float vs = v*ws, vd = v*wd;
  #pragma unroll
  for (int off = 32; off > 0; off >>= 1){
    vs += __shfl_down(vs, off);
    vd += __shfl_down(vd, off);
  }
  if (lane == 0){ asrc[node] = vs; adst[node] = vd; }
}

__global__ __launch_bounds__(64) void aggregate2_kernel(const float* __restrict__ H2v,
    const int* __restrict__ offsets, const int* __restrict__ ssrc,
    const float* __restrict__ asrc, const float* __restrict__ adst,
    const float* __restrict__ bias, float* __restrict__ OUT){
  int d = blockIdx.x;
  int lane = threadIdx.x;
  int beg = offsets[d], end = offsets[d+1];
  int deg = end - beg;
  float ad = adst[d];
  float pm = -1e30f;
  for (int i = lane; i < deg; i += 64){
    int s = ssrc[beg+i];
    float e = asrc[s] + ad; e = (e>0.f)?e:NEG_SLOPE*e;
    pm = fmaxf(pm, e);
  }
  #pragma unroll
  for (int off = 32; off > 0; off >>= 1) pm = fmaxf(pm, __shfl_xor(pm, off));
  float ps = 0.f;
  for (int i = lane; i < deg; i += 64){
    int s = ssrc[beg+i];
    float e = asrc[s] + ad; e=(e>0.f)?e:NEG_SLOPE*e;
    ps += __expf(e - pm);
  }
  #pragma unroll
  for (int off = 32; off > 0; off >>= 1) ps += __shfl_xor(ps, off);
  float inv = 1.f/ps;
  __shared__ float alS[64];
  __shared__ int sS[64];
  float acc = 0.f;
  for (int i0 = 0; i0 < deg; i0 += 64){
    int nch = min(64, deg - i0);
    if (lane < nch){
      int s = ssrc[beg+i0+lane];
      float e = asrc[s]+ad; e=(e>0.f)?e:NEG_SLOPE*e;
      alS[lane] = __expf(e-pm)*inv;
      sS[lane] = s;
    }
    __syncthreads();
    for (int i = 0; i < nch; ++i){
      if (lane < 40) acc += alS[i] * H2v[(size_t)sS[i]*40 + lane];
    }
    __syncthreads();
  }
  float logit = (lane<40) ? (acc + bias[lane]) : -1e30f;
  float mm = logit;
  #pragma unroll
  for (int off = 32; off > 0; off >>= 1) mm = fmaxf(mm, __shfl_xor(mm, off));
  float ex = (lane<40) ? __expf(logit-mm) : 0.f;
  float ss = ex;
  #pragma unroll
  for (int off = 32; off > 0; off >>= 1) ss += __shfl_xor(ss, off);
  if (lane < 40) OUT[(size_t)d*40 + lane] = logit - mm - logf(ss);
}

// ---------------- launch ----------------

extern "C" void kernel_launch(void* const* d_in, const int* in_sizes, int n_in,
                              void* d_out, int out_size, void* d_ws, size_t ws_size,
                              hipStream_t stream){
  const float* x   = (const float*)d_in[0];
  const int*   ei  = (const int*)d_in[1];
  const float* W0  = (const float*)d_in[2];
  const float* as0 = (const float*)d_in[3];
  const float* ad0 = (const float*)d_in[4];
  const float* b0  = (const float*)d_in[5];
  const float* W1  = (const float*)d_in[6];
  const float* as1 = (const float*)d_in[7];
  const float* ad1 = (const float*)d_in[8];
  const float* b1  = (const float*)d_in[9];
  const float* W2  = (const float*)d_in[10];
  const float* as2 = (const float*)d_in[11];
  const float* ad2 = (const float*)d_in[12];
  const float* b2  = (const float*)d_in[13];
  float* out = (float*)d_out;

  char* p = (char*)d_ws;
  auto alloc = [&](size_t bytes)->void*{
    void* r = (void*)p; p += (bytes + 255) & ~(size_t)255; return r;
  };
  float* F1    = (float*)alloc((size_t)M_PAD*512*4);
  unsigned short* FbS = (unsigned short*)alloc((size_t)M_PAD*512*2);
  float* ASRC  = (float*)alloc((size_t)N_NODES*8*4);
  float* ADST  = (float*)alloc((size_t)N_NODES*8*4);
  unsigned* EA = (unsigned*)alloc((size_t)8*TOT_EDGES*4);
  float* H2v   = (float*)alloc((size_t)N_NODES*40*4);
  float* ASRC2 = (float*)alloc((size_t)N_NODES*4);
  float* ADST2 = (float*)alloc((size_t)N_NODES*4);
  int* counts  = (int*)alloc((size_t)N_NODES*4);
  int* offsets = (int*)alloc((size_t)(N_NODES+1)*4);
  int* cursor  = (int*)alloc((size_t)N_NODES*4);
  int* ssrc    = (int*)alloc((size_t)TOT_EDGES*4);
  int* partial = (int*)alloc((size_t)N_NODES*4);
  int* chunksum= (int*)alloc(64*4);
  int* carry   = (int*)alloc(64*4);
  unsigned short* BTh  = (unsigned short*)alloc((size_t)512*512*2);
  unsigned short* BTl  = (unsigned short*)alloc((size_t)512*512*2);
  unsigned short* BT2h = (unsigned short*)alloc((size_t)128*512*2);
  unsigned short* BT2l = (unsigned short*)alloc((size_t)128*512*2);

  // CSR build (same graph for all 3 layers)
  hipMemsetAsync(counts, 0, (size_t)N_NODES*4, stream);
  hist_kernel<<<(TOT_EDGES+255)/256, 256, 0, stream>>>(ei, counts);
  scan1_kernel<<<N_CHUNKS, 1024, 0, stream>>>(counts, partial, chunksum);
  scan2_kernel<<<1, 64, 0, stream>>>(chunksum, carry);
  scan3_kernel<<<(N_NODES+255)/256, 256, 0, stream>>>(partial, counts, carry, offsets, cursor);
  scatter_kernel<<<(TOT_EDGES+255)/256, 256, 0, stream>>>(ei, cursor, ssrc);

  int mt = M_PAD / 128;   // 391
  int spmm_blocks = 2 * 8 * 3125;   // 2 halves x 8 slices x 3125 chunks (16 dst each)

  // layer 0: x[50000,128] @ W0[128,512]
  convert_BT<<<(128*512+255)/256, 256, 0, stream>>>(W0, BTh, BTl, 128, 512);
  mfma_gemm<<<dim3(4, mt), 256, 0, stream>>>(x, BTh, BTl, nullptr, FbS,
                                             as0, ad0, ASRC, ADST, N_NODES, 128, 512);
  softmax_stats<<<(N_NODES+3)/4, 256, 0, stream>>>(offsets, ssrc, ASRC, ADST, EA);
  spmm_kernel<<<spmm_blocks, 256, 0, stream>>>(FbS, offsets, EA, b0, F1, 1);

  // layer 1: F1[50000,512] @ W1[512,512]
  convert_BT<<<(512*512+255)/256, 256, 0, stream>>>(W1, BTh, BTl, 512, 512);
  mfma_gemm<<<dim3(4, mt), 256, 0, stream>>>(F1, BTh, BTl, nullptr, FbS,
                                             as1, ad1, ASRC, ADST, N_NODES, 512, 512);
  softmax_stats<<<(N_NODES+3)/4, 256, 0, stream>>>(offsets, ssrc, ASRC, ADST, EA);
  spmm_kernel<<<spmm_blocks, 256, 0, stream>>>(FbS, offsets, EA, b1, F1, 1);

  // layer 2: F1[50000,512] @ W2[512,40]  (mfma with zero-padded B, f32 C out)
  convert_BT2<<<(128*512+255)/256, 256, 0, stream>>>(W2, BT2h, BT2l);
  mfma_gemm<<<dim3(1, mt), 256, 0, stream>>>(F1, BT2h, BT2l, H2v, nullptr,
                                             nullptr, nullptr, nullptr, nullptr, N_NODES, 512, 40);
  attn_coef2_kernel<<<(N_NODES*64+255)/256, 256, 0, stream>>>(H2v, as2, ad2, ASRC2, ADST2);
  aggregate2_kernel<<<N_NODES, 64, 0, stream>>>(H2v, offsets, ssrc, ASRC2, ADST2, b2, out);
}

// Round 10
// 767.596 us; speedup vs baseline: 1.7090x; 1.0016x over previous
//
#include <hip/hip_runtime.h>
#include <hip/hip_bf16.h>
#include <hip/hip_fp16.h>
#include <math.h>

#define N_NODES 50000
#define N_EDGES 800000
#define TOT_EDGES (N_EDGES + N_NODES)
#define NEG_SLOPE 0.2f
#define M_PAD 50048
#define N_CHUNKS ((N_NODES + 1023) / 1024)

typedef __attribute__((ext_vector_type(8))) short bf16x8;
typedef __attribute__((ext_vector_type(4))) float f32x4;
typedef __attribute__((ext_vector_type(8))) unsigned short u16x8;

__device__ __forceinline__ unsigned short f2bf(float f){
  union { float f; unsigned u; } x; x.f = f;
  unsigned r = x.u + 0x7FFF + ((x.u >> 16) & 1);
  return (unsigned short)(r >> 16);
}
__device__ __forceinline__ float bf2f(unsigned short h){
  union { unsigned u; float f; } x; x.u = ((unsigned)h) << 16;
  return x.f;
}
__device__ __forceinline__ void gl_lds16(const void* g, void* l){
  __builtin_amdgcn_global_load_lds(
    (const __attribute__((address_space(1))) unsigned int*)g,
    (__attribute__((address_space(3))) unsigned int*)l, 16, 0, 0);
}

// ---------------- CSR build ----------------

__global__ void hist_kernel(const int* __restrict__ ei, int* __restrict__ counts){
  int e = blockIdx.x*256 + threadIdx.x;
  if (e >= TOT_EDGES) return;
  int d = (e < N_EDGES) ? ei[N_EDGES + e] : (e - N_EDGES);
  atomicAdd(&counts[d], 1);
}

__global__ void scan1_kernel(const int* __restrict__ counts, int* __restrict__ partial,
                             int* __restrict__ chunksum){
  __shared__ int sm[1024];
  int t = threadIdx.x;
  int idx = blockIdx.x*1024 + t;
  int v = (idx < N_NODES) ? counts[idx] : 0;
  sm[t] = v;
  __syncthreads();
  for (int off = 1; off < 1024; off <<= 1){
    int u = (t >= off) ? sm[t-off] : 0;
    __syncthreads();
    sm[t] += u;
    __syncthreads();
  }
  if (idx < N_NODES) partial[idx] = sm[t];
  if (t == 1023) chunksum[blockIdx.x] = sm[1023];
}

__global__ void scan2_kernel(const int* __restrict__ chunksum, int* __restrict__ carry){
  if (threadIdx.x == 0){
    int c = 0;
    for (int i = 0; i < N_CHUNKS; ++i){ carry[i] = c; c += chunksum[i]; }
  }
}

__global__ void scan3_kernel(const int* __restrict__ partial, const int* __restrict__ counts,
                             const int* __restrict__ carry, int* __restrict__ offsets,
                             int* __restrict__ cursor){
  int idx = blockIdx.x*256 + threadIdx.x;
  if (idx >= N_NODES) return;
  int inc = partial[idx] + carry[idx >> 10];
  offsets[idx+1] = inc;
  cursor[idx] = inc - counts[idx];
  if (idx == 0) offsets[0] = 0;
}

__global__ void scatter_kernel(const int* __restrict__ ei, int* __restrict__ cursor,
                               int* __restrict__ ssrc){
  int e = blockIdx.x*256 + threadIdx.x;
  if (e >= TOT_EDGES) return;
  int s, d;
  if (e < N_EDGES){ s = ei[e]; d = ei[N_EDGES+e]; } else { s = e - N_EDGES; d = s; }
  int pos = atomicAdd(&cursor[d], 1);
  ssrc[pos] = s;
}

// ---------------- weight split+transpose: BT[n][k] = B[k][n] as bf16 hi/lo ----------------

__global__ void convert_BT(const float* __restrict__ B, unsigned short* __restrict__ BTh,
                           unsigned short* __restrict__ BTl, int K, int N){
  int id = blockIdx.x*256 + threadIdx.x;
  if (id >= K*N) return;
  int n = id / K, k = id - n*K;
  float v = B[(size_t)k*N + n];
  unsigned short h = f2bf(v);
  unsigned short l = f2bf(v - bf2f(h));
  BTh[id] = h; BTl[id] = l;
}

// layer-2 weights [512,40] -> padded BT2 [128][512]
__global__ void convert_BT2(const float* __restrict__ B, unsigned short* __restrict__ BTh,
                            unsigned short* __restrict__ BTl){
  int id = blockIdx.x*256 + threadIdx.x;
  if (id >= 128*512) return;
  int n = id >> 9, k = id & 511;
  float v = (n < 40) ? B[(size_t)k*40 + n] : 0.f;
  unsigned short h = f2bf(v);
  unsigned short l = f2bf(v - bf2f(h));
  BTh[id] = h; BTl[id] = l;
}

// layer-0 input x [50000,128] f32 -> xh/xl [M_PAD][128] bf16 hi/lo (pad rows zero)
__global__ void split_x(const float* __restrict__ X, unsigned short* __restrict__ Xh,
                        unsigned short* __restrict__ Xl){
  int id = blockIdx.x*256 + threadIdx.x;
  if (id >= M_PAD*128) return;
  int row = id >> 7;
  float v = (row < N_NODES) ? X[(size_t)row*128 + (id & 127)] : 0.f;
  unsigned short h = f2bf(v);
  unsigned short l = f2bf(v - bf2f(h));
  Xh[id] = h; Xl[id] = l;
}

// ---------------- split-bf16 MFMA GEMM (pre-split A) + fused attn-coef + slice-blocked out ----
// 128x128 tile, BK=32, 4 waves, 3-term split (Ah*Bh + Al*Bh + Ah*Bl).
// A and B both staged via global_load_lds with pre-swizzled source (rule #21) — no staging VALU.

__global__ __launch_bounds__(256, 2) void mfma_gemm(
    const unsigned short* __restrict__ Ah_g, const unsigned short* __restrict__ Al_g,
    const unsigned short* __restrict__ BTh, const unsigned short* __restrict__ BTl,
    float* __restrict__ C, unsigned short* __restrict__ FbS,
    const float* __restrict__ att_s, const float* __restrict__ att_d,
    float* __restrict__ asrc, float* __restrict__ adst,
    int M, int K, int Nc)
{
  __shared__ unsigned short sAh[128*32];
  __shared__ unsigned short sAl[128*32];
  __shared__ unsigned short sBh[128*32];
  __shared__ unsigned short sBl[128*32];

  const int tid = threadIdx.x;
  const int lane = tid & 63;
  const int wid = tid >> 6;
  const int wr = wid >> 1, wc = wid & 1;
  const int bm = blockIdx.y * 128, bn = blockIdx.x * 128;
  const int lr = lane & 15, kg = lane >> 4;

  // staging source offsets (pre-swizzled): thread o stages row=o>>2, 16B chunk ch=o&3
  size_t agoff[2], bgoff[2];
  #pragma unroll
  for (int i = 0; i < 2; ++i){
    int o = tid + i*256;
    int row = o >> 2, ch = o & 3;
    int sc = ch ^ ((row >> 1) & 3);
    agoff[i] = (size_t)(bm + row)*K + sc*8;
    bgoff[i] = (size_t)(bn + row)*K + sc*8;
  }
  // fragment ds_read offsets (swizzled), constant across k-steps
  int aoff[4], boff[4];
  #pragma unroll
  for (int i = 0; i < 4; ++i){
    int row = wr*64 + i*16 + lr;
    aoff[i] = row*32 + (kg ^ ((row >> 1) & 3))*8;
    int col = wc*64 + i*16 + lr;
    boff[i] = col*32 + (kg ^ ((col >> 1) & 3))*8;
  }

  auto stage = [&](int k0){
    #pragma unroll
    for (int i = 0; i < 2; ++i){
      gl_lds16(Ah_g + agoff[i] + k0, &sAh[(tid + i*256)*8]);
      gl_lds16(Al_g + agoff[i] + k0, &sAl[(tid + i*256)*8]);
      gl_lds16(BTh + bgoff[i] + k0, &sBh[(tid + i*256)*8]);
      gl_lds16(BTl + bgoff[i] + k0, &sBl[(tid + i*256)*8]);
    }
  };

  f32x4 acc[4][4];
  #pragma unroll
  for (int i = 0; i < 4; ++i)
    #pragma unroll
    for (int j = 0; j < 4; ++j)
      acc[i][j] = (f32x4){0.f, 0.f, 0.f, 0.f};

  stage(0);
  __syncthreads();
  int k0 = 0;
  while (true){
    bf16x8 ah[4], al[4], bh[4], bl[4];
    #pragma unroll
    for (int i = 0; i < 4; ++i){
      ah[i] = *(const bf16x8*)&sAh[aoff[i]];
      al[i] = *(const bf16x8*)&sAl[aoff[i]];
      bh[i] = *(const bf16x8*)&sBh[boff[i]];
      bl[i] = *(const bf16x8*)&sBl[boff[i]];
    }
    #pragma unroll
    for (int i = 0; i < 4; ++i)
      #pragma unroll
      for (int j = 0; j < 4; ++j){
        acc[i][j] = __builtin_amdgcn_mfma_f32_16x16x32_bf16(ah[i], bh[j], acc[i][j], 0, 0, 0);
        acc[i][j] = __builtin_amdgcn_mfma_f32_16x16x32_bf16(al[i], bh[j], acc[i][j], 0, 0, 0);
        acc[i][j] = __builtin_amdgcn_mfma_f32_16x16x32_bf16(ah[i], bl[j], acc[i][j], 0, 0, 0);
      }
    int kn = k0 + 32;
    if (kn >= K) break;
    __syncthreads();
    stage(kn);
    __syncthreads();
    k0 = kn;
  }

  // fused attention coefficients: each wave owns exactly one head's 64 cols
  if (att_s){
    int head = (bn >> 6) + wc;
    float ws_[4], wd_[4];
    #pragma unroll
    for (int j = 0; j < 4; ++j){
      ws_[j] = att_s[head*64 + j*16 + lr];
      wd_[j] = att_d[head*64 + j*16 + lr];
    }
    #pragma unroll
    for (int i = 0; i < 4; ++i){
      #pragma unroll
      for (int r = 0; r < 4; ++r){
        float vs = 0.f, vd = 0.f;
        #pragma unroll
        for (int j = 0; j < 4; ++j){
          vs += acc[i][j][r] * ws_[j];
          vd += acc[i][j][r] * wd_[j];
        }
        #pragma unroll
        for (int m = 1; m < 16; m <<= 1){
          vs += __shfl_xor(vs, m);
          vd += __shfl_xor(vd, m);
        }
        int gm = bm + wr*64 + i*16 + kg*4 + r;
        if ((lane & 15) == 0 && gm < M){
          asrc[gm*8 + head] = vs;
          adst[gm*8 + head] = vd;
        }
      }
    }
  }

  // epilogue: C/D layout col=lane&15, row=(lane>>4)*4+reg  [m89]
  #pragma unroll
  for (int i = 0; i < 4; ++i){
    int gm0 = bm + wr*64 + i*16 + kg*4;
    #pragma unroll
    for (int j = 0; j < 4; ++j){
      int gn = bn + wc*64 + j*16 + lr;
      int sl = gn >> 5, cc = gn & 31;
      #pragma unroll
      for (int r = 0; r < 4; ++r){
        int gm = gm0 + r;
        if (gm < M){
          if (C && gn < Nc) C[(size_t)gm*Nc + gn] = acc[i][j][r];
          if (FbS) FbS[(size_t)sl*(M_PAD*32) + (size_t)gm*32 + cc] = f2bf(acc[i][j][r]);
        }
      }
    }
  }
}

// ---------------- softmax stats + packed u32 (src | f16(alpha)<<16) stream EA[h][edge] ----------------

__global__ __launch_bounds__(256) void softmax_stats(const int* __restrict__ offsets,
    const int* __restrict__ ssrc, const float* __restrict__ asrc,
    const float* __restrict__ adst, unsigned* __restrict__ EA){
  int w = threadIdx.x >> 6;
  int lane = threadIdx.x & 63;
  int d = blockIdx.x*4 + w;
  if (d >= N_NODES) return;
  int h = lane & 7, grp = lane >> 3;
  int beg = offsets[d], end = offsets[d+1];
  float ad = adst[d*8+h];
  float pm = -1e30f;
  for (int i = beg+grp; i < end; i += 8){
    int s = ssrc[i];
    float e = asrc[s*8+h] + ad;
    e = (e > 0.f) ? e : NEG_SLOPE*e;
    pm = fmaxf(pm, e);
  }
  pm = fmaxf(pm, __shfl_xor(pm, 8));
  pm = fmaxf(pm, __shfl_xor(pm, 16));
  pm = fmaxf(pm, __shfl_xor(pm, 32));
  float ps = 0.f;
  for (int i = beg+grp; i < end; i += 8){
    int s = ssrc[i];
    float e = asrc[s*8+h] + ad;
    e = (e > 0.f) ? e : NEG_SLOPE*e;
    ps += __expf(e - pm);
  }
  ps += __shfl_xor(ps, 8);
  ps += __shfl_xor(ps, 16);
  ps += __shfl_xor(ps, 32);
  float iv = 1.f / ps;
  unsigned* Eh = EA + (size_t)h * TOT_EDGES;
  for (int i = beg+grp; i < end; i += 8){
    int s = ssrc[i];
    float e = asrc[s*8+h] + ad;
    e = (e > 0.f) ? e : NEG_SLOPE*e;
    float al = __expf(e - pm) * iv;
    union { __half hh; unsigned short u; } cv; cv.hh = __float2half(al);
    unsigned pk = (unsigned)s | ((unsigned)cv.u << 16);
    __builtin_nontemporal_store(pk, &Eh[i]);
  }
}

// ---------------- XCD-pinned channel-sliced SpMM, 4-dst-per-wave, LDS-staged EA ----------------
// FbS layout [16][M_PAD][32ch]; slice = bid%8 (+8 second half) pins each 3.2MB slice to one
// XCD's L2. Block = 16 contiguous dst -> contiguous EA range staged coalesced into LDS.
// Output written directly as bf16 hi/lo pair (next layer's GEMM A operand) via ext-vector
// stores with compile-time lane indices (R9 post-mortem: ushort4 ptr-index UB fixed).

__global__ __launch_bounds__(256) void spmm_kernel(const unsigned short* __restrict__ FbS,
    const int* __restrict__ offsets, const unsigned* __restrict__ EA,
    const float* __restrict__ bias, unsigned short* __restrict__ Fh,
    unsigned short* __restrict__ Fl, int do_relu){
  __shared__ unsigned sEA[1024];
  int bid = blockIdx.x;
  int half = (bid >= 25000) ? 1 : 0;
  int r = bid - half*25000;
  int slice = (r & 7) + half*8;
  int chunk = r >> 3;               // 0..3124
  int lane = threadIdx.x & 63;
  int wid = threadIdx.x >> 6;
  int dsub = lane >> 4;             // 4 dst per wave
  int slot = (lane >> 2) & 3;       // 4 edge slots
  int ch = lane & 3;                // 4 ch-lanes x 8 ch
  int dbase = chunk*16;
  int d = dbase + wid*4 + dsub;
  int h = slice >> 1;
  const unsigned short* Ft = FbS + (size_t)slice * (M_PAD*32);
  const unsigned* Eh = EA + (size_t)h * TOT_EDGES;
  int beg0 = offsets[dbase];
  int cnt = min(offsets[dbase+16] - beg0, 1024);
  for (int i = threadIdx.x; i < cnt; i += 256)
    sEA[i] = __builtin_nontemporal_load(&Eh[beg0 + i]);
  __syncthreads();
  int beg = offsets[d], end = offsets[d+1];
  float a0=0.f,a1=0.f,a2=0.f,a3=0.f,a4=0.f,a5=0.f,a6=0.f,a7=0.f;
  #pragma unroll 2
  for (int i = beg + slot; i < end; i += 4){
    int idx = i - beg0;
    unsigned ea = (idx < cnt) ? sEA[idx] : __builtin_nontemporal_load(&Eh[i]);
    int s = ea & 0xFFFF;
    union { unsigned short u; __half hh; } dv; dv.u = (unsigned short)(ea >> 16);
    float al = __half2float(dv.hh);
    uint4 v = *(const uint4*)&Ft[(size_t)s*32 + ch*8];
    union { unsigned q; float f; } lo, hi;
    lo.q = v.x << 16; hi.q = v.x & 0xffff0000u; a0 += al*lo.f; a1 += al*hi.f;
    lo.q = v.y << 16; hi.q = v.y & 0xffff0000u; a2 += al*lo.f; a3 += al*hi.f;
    lo.q = v.z << 16; hi.q = v.z & 0xffff0000u; a4 += al*lo.f; a5 += al*hi.f;
    lo.q = v.w << 16; hi.q = v.w & 0xffff0000u; a6 += al*lo.f; a7 += al*hi.f;
  }
  // reduce over slot (lane bits 2-3)
  a0 += __shfl_xor(a0, 4); a0 += __shfl_xor(a0, 8);
  a1 += __shfl_xor(a1, 4); a1 += __shfl_xor(a1, 8);
  a2 += __shfl_xor(a2, 4); a2 += __shfl_xor(a2, 8);
  a3 += __shfl_xor(a3, 4); a3 += __shfl_xor(a3, 8);
  a4 += __shfl_xor(a4, 4); a4 += __shfl_xor(a4, 8);
  a5 += __shfl_xor(a5, 4); a5 += __shfl_xor(a5, 8);
  a6 += __shfl_xor(a6, 4); a6 += __shfl_xor(a6, 8);
  a7 += __shfl_xor(a7, 4); a7 += __shfl_xor(a7, 8);
  if (slot == 0){
    int c = slice*32 + ch*8;
    float4 b0v = *(const float4*)&bias[c];
    float4 b1v = *(const float4*)&bias[c+4];
    float oo[8];
    oo[0]=a0+b0v.x; oo[1]=a1+b0v.y; oo[2]=a2+b0v.z; oo[3]=a3+b0v.w;
    oo[4]=a4+b1v.x; oo[5]=a5+b1v.y; oo[6]=a6+b1v.z; oo[7]=a7+b1v.w;
    u16x8 vh, vl;
    #pragma unroll
    for (int q = 0; q < 8; ++q){
      float v = oo[q];
      if (do_relu) v = fmaxf(v, 0.f);
      unsigned short hb = f2bf(v);
      vh[q] = hb;
      vl[q] = f2bf(v - bf2f(hb));
    }
    size_t base = (size_t)d*512 + c;
    *(u16x8*)&Fh[base] = vh;
    *(u16x8*)&Fl[base] = vl;
  }
}

// ---------------- layer 2: H=1 C=40 ----------------

__global__ void attn_coef2_kernel(const float* __restrict__ H2v, const float* __restrict__ as2,
                                  const float* __restrict__ ad2,
                                  float* __restrict__ asrc, float* __restrict__ adst){
  int gid = blockIdx.x*256 + threadIdx.x;
  int node = gid >> 6;
  int lane = threadIdx.x & 63;
  if (node >= N_NODES) return;
  float v = 0.f, ws = 0.f, wd = 0.f;
  if (lane < 40){ v = H2v[(size_t)node*40 + lane]; ws = as2[lane]; wd = ad2[lane]; }
  float vs = v*ws, vd = v*wd;
  #pragma unroll
  for (int off = 32; off > 0; off >>= 1){
    vs += __shfl_down(vs, off);
    vd += __shfl_down(vd, off);
  }
  if (lane == 0){ asrc[node] = vs; adst[node] = vd; }
}

__global__ __launch_bounds__(64) void aggregate2_kernel(const float* __restrict__ H2v,
    const int* __restrict__ offsets, const int* __restrict__ ssrc,
    const float* __restrict__ asrc, const float* __restrict__ adst,
    const float* __restrict__ bias, float* __restrict__ OUT){
  int d = blockIdx.x;
  int lane = threadIdx.x;
  int beg = offsets[d], end = offsets[d+1];
  int deg = end - beg;
  float ad = adst[d];
  float pm = -1e30f;
  for (int i = lane; i < deg; i += 64){
    int s = ssrc[beg+i];
    float e = asrc[s] + ad; e = (e>0.f)?e:NEG_SLOPE*e;
    pm = fmaxf(pm, e);
  }
  #pragma unroll
  for (int off = 32; off > 0; off >>= 1) pm = fmaxf(pm, __shfl_xor(pm, off));
  float ps = 0.f;
  for (int i = lane; i < deg; i += 64){
    int s = ssrc[beg+i];
    float e = asrc[s] + ad; e=(e>0.f)?e:NEG_SLOPE*e;
    ps += __expf(e - pm);
  }
  #pragma unroll
  for (int off = 32; off > 0; off >>= 1) ps += __shfl_xor(ps, off);
  float inv = 1.f/ps;
  __shared__ float alS[64];
  __shared__ int sS[64];
  float acc = 0.f;
  for (int i0 = 0; i0 < deg; i0 += 64){
    int nch = min(64, deg - i0);
    if (lane < nch){
      int s = ssrc[beg+i0+lane];
      float e = asrc[s]+ad; e=(e>0.f)?e:NEG_SLOPE*e;
      alS[lane] = __expf(e-pm)*inv;
      sS[lane] = s;
    }
    __syncthreads();
    for (int i = 0; i < nch; ++i){
      if (lane < 40) acc += alS[i] * H2v[(size_t)sS[i]*40 + lane];
    }
    __syncthreads();
  }
  float logit = (lane<40) ? (acc + bias[lane]) : -1e30f;
  float mm = logit;
  #pragma unroll
  for (int off = 32; off > 0; off >>= 1) mm = fmaxf(mm, __shfl_xor(mm, off));
  float ex = (lane<40) ? __expf(logit-mm) : 0.f;
  float ss = ex;
  #pragma unroll
  for (int off = 32; off > 0; off >>= 1) ss += __shfl_xor(ss, off);
  if (lane < 40) OUT[(size_t)d*40 + lane] = logit - mm - logf(ss);
}

// ---------------- launch ----------------

extern "C" void kernel_launch(void* const* d_in, const int* in_sizes, int n_in,
                              void* d_out, int out_size, void* d_ws, size_t ws_size,
                              hipStream_t stream){
  const float* x   = (const float*)d_in[0];
  const int*   ei  = (const int*)d_in[1];
  const float* W0  = (const float*)d_in[2];
  const float* as0 = (const float*)d_in[3];
  const float* ad0 = (const float*)d_in[4];
  const float* b0  = (const float*)d_in[5];
  const float* W1  = (const float*)d_in[6];
  const float* as1 = (const float*)d_in[7];
  const float* ad1 = (const float*)d_in[8];
  const float* b1  = (const float*)d_in[9];
  const float* W2  = (const float*)d_in[10];
  const float* as2 = (const float*)d_in[11];
  const float* ad2 = (const float*)d_in[12];
  const float* b2  = (const float*)d_in[13];
  float* out = (float*)d_out;

  char* p = (char*)d_ws;
  auto alloc = [&](size_t bytes)->void*{
    void* r = (void*)p; p += (bytes + 255) & ~(size_t)255; return r;
  };
  unsigned short* F1h = (unsigned short*)alloc((size_t)M_PAD*512*2);
  unsigned short* F1l = (unsigned short*)alloc((size_t)M_PAD*512*2);
  unsigned short* FbS = (unsigned short*)alloc((size_t)M_PAD*512*2);
  unsigned short* Xh  = (unsigned short*)alloc((size_t)M_PAD*128*2);
  unsigned short* Xl  = (unsigned short*)alloc((size_t)M_PAD*128*2);
  float* ASRC  = (float*)alloc((size_t)N_NODES*8*4);
  float* ADST  = (float*)alloc((size_t)N_NODES*8*4);
  unsigned* EA = (unsigned*)alloc((size_t)8*TOT_EDGES*4);
  float* H2v   = (float*)alloc((size_t)N_NODES*40*4);
  float* ASRC2 = (float*)alloc((size_t)N_NODES*4);
  float* ADST2 = (float*)alloc((size_t)N_NODES*4);
  int* counts  = (int*)alloc((size_t)N_NODES*4);
  int* offsets = (int*)alloc((size_t)(N_NODES+1)*4);
  int* cursor  = (int*)alloc((size_t)N_NODES*4);
  int* ssrc    = (int*)alloc((size_t)TOT_EDGES*4);
  int* partial = (int*)alloc((size_t)N_NODES*4);
  int* chunksum= (int*)alloc(64*4);
  int* carry   = (int*)alloc(64*4);
  unsigned short* BTh  = (unsigned short*)alloc((size_t)512*512*2);
  unsigned short* BTl  = (unsigned short*)alloc((size_t)512*512*2);
  unsigned short* BT2h = (unsigned short*)alloc((size_t)128*512*2);
  unsigned short* BT2l = (unsigned short*)alloc((size_t)128*512*2);

  // zero the pad rows of F1h/F1l once (read by GEMM A staging for tiles past M)
  hipMemsetAsync(F1h + (size_t)N_NODES*512, 0, (size_t)(M_PAD-N_NODES)*512*2, stream);
  hipMemsetAsync(F1l + (size_t)N_NODES*512, 0, (size_t)(M_PAD-N_NODES)*512*2, stream);

  // CSR build (same graph for all 3 layers)
  hipMemsetAsync(counts, 0, (size_t)N_NODES*4, stream);
  hist_kernel<<<(TOT_EDGES+255)/256, 256, 0, stream>>>(ei, counts);
  scan1_kernel<<<N_CHUNKS, 1024, 0, stream>>>(counts, partial, chunksum);
  scan2_kernel<<<1, 64, 0, stream>>>(chunksum, carry);
  scan3_kernel<<<(N_NODES+255)/256, 256, 0, stream>>>(partial, counts, carry, offsets, cursor);
  scatter_kernel<<<(TOT_EDGES+255)/256, 256, 0, stream>>>(ei, cursor, ssrc);

  int mt = M_PAD / 128;   // 391
  int spmm_blocks = 2 * 8 * 3125;   // 2 halves x 8 slices x 3125 chunks (16 dst each)

  // layer 0: x[50000,128] @ W0[128,512]
  split_x<<<(M_PAD*128+255)/256, 256, 0, stream>>>(x, Xh, Xl);
  convert_BT<<<(128*512+255)/256, 256, 0, stream>>>(W0, BTh, BTl, 128, 512);
  mfma_gemm<<<dim3(4, mt), 256, 0, stream>>>(Xh, Xl, BTh, BTl, nullptr, FbS,
                                             as0, ad0, ASRC, ADST, N_NODES, 128, 512);
  softmax_stats<<<(N_NODES+3)/4, 256, 0, stream>>>(offsets, ssrc, ASRC, ADST, EA);
  spmm_kernel<<<spmm_blocks, 256, 0, stream>>>(FbS, offsets, EA, b0, F1h, F1l, 1);

  // layer 1: F1[50000,512] @ W1[512,512]
  convert_BT<<<(512*512+255)/256, 256, 0, stream>>>(W1, BTh, BTl, 512, 512);
  mfma_gemm<<<dim3(4, mt), 256, 0, stream>>>(F1h, F1l, BTh, BTl, nullptr, FbS,
                                             as1, ad1, ASRC, ADST, N_NODES, 512, 512);
  softmax_stats<<<(N_NODES+3)/4, 256, 0, stream>>>(offsets, ssrc, ASRC, ADST, EA);
  spmm_kernel<<<spmm_blocks, 256, 0, stream>>>(FbS, offsets, EA, b1, F1h, F1l, 1);

  // layer 2: F1[50000,512] @ W2[512,40]  (mfma with zero-padded B, f32 C out)
  convert_BT2<<<(128*512+255)/256, 256, 0, stream>>>(W2, BT2h, BT2l);
  mfma_gemm<<<dim3(1, mt), 256, 0, stream>>>(F1h, F1l, BT2h, BT2l, H2v, nullptr,
                                             nullptr, nullptr, nullptr, nullptr, N_NODES, 512, 40);
  attn_coef2_kernel<<<(N_NODES*64+255)/256, 256, 0, stream>>>(H2v, as2, ad2, ASRC2, ADST2);
  aggregate2_kernel<<<N_NODES, 64, 0, stream>>>(H2v, offsets, ssrc, ASRC2, ADST2, b2, out);
}